// Round 4
// baseline (237.621 us; speedup 1.0000x reference)
//
#include <hip/hip_runtime.h>
#include <hip/hip_bf16.h>

typedef unsigned short u16;
typedef unsigned int u32;
typedef __attribute__((ext_vector_type(8))) short short8;
typedef __attribute__((ext_vector_type(4))) float f32x4;

// cheap RNE f32->bf16 (finite values only)
__device__ __forceinline__ u16 f2b(float f) {
  u32 u = __builtin_bit_cast(u32, f);
  u += 0x7fffu + ((u >> 16) & 1u);
  return (u16)(u >> 16);
}
// hardware packed f32x2 -> bf16x2 (lo = a, hi = b), RNE
__device__ __forceinline__ u32 cvtpk(float a, float b) {
  u32 r;
  asm("v_cvt_pk_bf16_f32 %0, %1, %2" : "=v"(r) : "v"(a), "v"(b));
  return r;
}
__device__ __forceinline__ float b2f(u16 u) {
  u32 x = ((u32)u) << 16;
  return __builtin_bit_cast(float, x);
}
__device__ __forceinline__ void load_lds16(const u16* g, u16* l) {
  __builtin_amdgcn_global_load_lds(
      (const __attribute__((address_space(1))) void*)(uintptr_t)g,
      (__attribute__((address_space(3))) void*)(u32)(uintptr_t)l, 16, 0, 0);
}

#define LOG2E 1.4426950408889634f

// k-slot permutation (64-granular): slot(k) = (k>>6)*64 + (k&15)*4 + ((k>>4)&3)

// ---- K_msa: LayerNorm(msa_act) -> bf16. 8 rows/wave, 8 independent float4
//      loads per thread (MLP is the lever; 32-VGPR regalloc serializing
//      loads was a 2.6x regression in round 1). ----
__global__ __launch_bounds__(256) void k_msa(
    const float* __restrict__ msa, const float* __restrict__ qns,
    const float* __restrict__ qnb, u16* __restrict__ xb) {
  const int tid = threadIdx.x, blk = blockIdx.x;
  const int wid = tid >> 6, lane = tid & 63;
  const int r = lane >> 3, c = lane & 7;
  const int row = blk * 32 + wid * 8 + r;
  const float* src = msa + (size_t)row * 256 + c * 4;
  float4 v[8];
#pragma unroll
  for (int it = 0; it < 8; it++)
    v[it] = *(const float4*)(src + it * 32);  // 8 independent 16B loads
  float s = 0.f, s2 = 0.f;
#pragma unroll
  for (int it = 0; it < 8; it++) {
    s += v[it].x + v[it].y + v[it].z + v[it].w;
    s2 += v[it].x * v[it].x + v[it].y * v[it].y + v[it].z * v[it].z + v[it].w * v[it].w;
  }
#pragma unroll
  for (int m = 1; m < 8; m <<= 1) { s += __shfl_xor(s, m); s2 += __shfl_xor(s2, m); }
  const float mu = s * (1.f / 256.f);
  const float rs = rsqrtf(s2 * (1.f / 256.f) - mu * mu + 1e-5f);
  u16* dst = xb + (size_t)row * 256 + c * 4;
#pragma unroll
  for (int it = 0; it < 8; it++) {
    const int c0 = it * 32 + c * 4;
    const float4 scv = *(const float4*)(qns + c0);
    const float4 biv = *(const float4*)(qnb + c0);
    uint2 o;
    o.x = cvtpk((v[it].x - mu) * rs * scv.x + biv.x, (v[it].y - mu) * rs * scv.y + biv.y);
    o.y = cvtpk((v[it].z - mu) * rs * scv.z + biv.z, (v[it].w - mu) * rs * scv.w + biv.w);
    *(uint2*)(dst + it * 32) = o;
  }
}

// ---- K_tr: weight transpose (blocks 0..79) + Wp/A/B precompute (block 80).
//      Wp[c][h] = LOG2E*pn_scale[c]*fw[c][h]; A[h] = sum_c Wp; B[h] = LOG2E*sum_c pnb*fw.
//      log2e pre-folded into Q weights (with 1/sqrt d), gate weights, and the
//      pair bias so k_attn can use raw v_exp (exp2) with no per-element mul. ----
__global__ __launch_bounds__(256) void k_tr(
    const float* __restrict__ qw, const float* __restrict__ kw,
    const float* __restrict__ vw, const float* __restrict__ gw,
    const float* __restrict__ ow, const float* __restrict__ pns,
    const float* __restrict__ pnb, const float* __restrict__ fw,
    u16* __restrict__ Wt, u16* __restrict__ OWt,
    float* __restrict__ wbuf, float* __restrict__ abuf) {
  const int tid = threadIdx.x;
  const int t = blockIdx.x;           // 0..80
  if (t == 80) {
    // ---- single wave: channels (lane, lane+64) ----
    if (tid >= 64) return;
    const int lane = tid;
    const float4 f0a = *(const float4*)(fw + lane * 8);
    const float4 f1a = *(const float4*)(fw + lane * 8 + 4);
    const float4 f0b = *(const float4*)(fw + (lane + 64) * 8);
    const float4 f1b = *(const float4*)(fw + (lane + 64) * 8 + 4);
    const float sa = pns[lane] * LOG2E, sb = pns[lane + 64] * LOG2E;
    const float ba = pnb[lane] * LOG2E, bb = pnb[lane + 64] * LOG2E;
    float4 w0a = {f0a.x * sa, f0a.y * sa, f0a.z * sa, f0a.w * sa};
    float4 w1a = {f1a.x * sa, f1a.y * sa, f1a.z * sa, f1a.w * sa};
    float4 w0b = {f0b.x * sb, f0b.y * sb, f0b.z * sb, f0b.w * sb};
    float4 w1b = {f1b.x * sb, f1b.y * sb, f1b.z * sb, f1b.w * sb};
    *(float4*)(wbuf + lane * 8) = w0a;
    *(float4*)(wbuf + lane * 8 + 4) = w1a;
    *(float4*)(wbuf + (lane + 64) * 8) = w0b;
    *(float4*)(wbuf + (lane + 64) * 8 + 4) = w1b;
    float pa[8] = {w0a.x + w0b.x, w0a.y + w0b.y, w0a.z + w0b.z, w0a.w + w0b.w,
                   w1a.x + w1b.x, w1a.y + w1b.y, w1a.z + w1b.z, w1a.w + w1b.w};
    float pb[8] = {ba * f0a.x + bb * f0b.x, ba * f0a.y + bb * f0b.y,
                   ba * f0a.z + bb * f0b.z, ba * f0a.w + bb * f0b.w,
                   ba * f1a.x + bb * f1b.x, ba * f1a.y + bb * f1b.y,
                   ba * f1a.z + bb * f1b.z, ba * f1a.w + bb * f1b.w};
#pragma unroll
    for (int m = 1; m < 64; m <<= 1) {
#pragma unroll
      for (int h = 0; h < 8; h++) {
        pa[h] += __shfl_xor(pa[h], m);
        pb[h] += __shfl_xor(pb[h], m);
      }
    }
    if (lane == 0) {
      *(float4*)(abuf)      = float4{pa[0], pa[1], pa[2], pa[3]};
      *(float4*)(abuf + 4)  = float4{pa[4], pa[5], pa[6], pa[7]};
      *(float4*)(abuf + 8)  = float4{pb[0], pb[1], pb[2], pb[3]};
      *(float4*)(abuf + 12) = float4{pb[4], pb[5], pb[6], pb[7]};
    }
    return;
  }
  __shared__ u16 tlds[64 * 66];
  const int proj = t >> 4, tile = t & 15;
  const int tr = (tile >> 2) * 64, tc = (tile & 3) * 64;
  const float* src = proj == 0 ? qw : proj == 1 ? kw : proj == 2 ? vw
                      : proj == 3 ? gw : ow;
  u16* dst = proj < 4 ? (Wt + proj * 65536) : OWt;
  // proj0: 1/sqrt(32) * log2e (folds softmax exp2 conversion into Q)
  // proj3: log2e (folds sigmoid exp2 conversion into gate)
  const float scale = proj == 0 ? 0.25503471881f
                      : proj == 3 ? LOG2E : 1.f;
  {
    const int rl = tid >> 2, cg = (tid & 3) * 16;
    const float* sp = src + (size_t)(tr + rl) * 256 + tc + cg;
    float4 a0 = *(const float4*)(sp);
    float4 a1 = *(const float4*)(sp + 4);
    float4 a2 = *(const float4*)(sp + 8);
    float4 a3 = *(const float4*)(sp + 12);
    float xs[16] = {a0.x, a0.y, a0.z, a0.w, a1.x, a1.y, a1.z, a1.w,
                    a2.x, a2.y, a2.z, a2.w, a3.x, a3.y, a3.z, a3.w};
#pragma unroll
    for (int j = 0; j < 16; j++)
      tlds[(cg + j) * 66 + rl] = f2b(xs[j] * scale);  // transposed store
  }
  __syncthreads();
  {
    const int cl = tid >> 2, ag = (tid & 3) * 16;
    union { uint4 q[2]; u16 u[16]; } uu;
#pragma unroll
    for (int j = 0; j < 16; j++) uu.u[j] = tlds[cl * 66 + ag + j];
    u16* dp = dst + (size_t)(tc + cl) * 256 + tr + ag;
    *(uint4*)(dp) = uu.q[0];
    *(uint4*)(dp + 8) = uu.q[1];
  }
}

// ---- K_pair: raw pair_act -> biasB[h][q][slot] via precomputed Wp/A/B.
//      ph[h] = r*(dot(x, Wp[:,h]) - mu*A[h]) + B[h]  (LN + log2e folded in). ----
__global__ __launch_bounds__(256) void k_pair(
    const float* __restrict__ pair, const float* __restrict__ wbuf,
    const float* __restrict__ abuf, float* __restrict__ biasB) {
  __shared__ float Wpt[8][132];
  __shared__ float plds[512];
  const int tid = threadIdx.x, pb = blockIdx.x;
  const int ra = tid >> 3, hh = tid & 7;
  const int R0 = pb * 64 + ra;                 // rows R0 and R0+32
  const float* p0 = pair + (size_t)R0 * 128 + hh * 4;
  const float* p1 = pair + (size_t)(R0 + 32) * 128 + hh * 4;
  float4 va[4], vb[4];
#pragma unroll
  for (int g = 0; g < 4; g++) va[g] = *(const float4*)(p0 + g * 32);
#pragma unroll
  for (int g = 0; g < 4; g++) vb[g] = *(const float4*)(p1 + g * 32);
  // reduce-scatter endpoint head for this lane:
  const int h = ((hh & 1) << 2) | (hh & 2) | ((hh >> 2) & 1);
  const float Ah = abuf[h], Bh = abuf[8 + h];
  // stage Wp transposed: thread t covers wbuf float4 t -> ch=t>>1, heads (t&1)*4..+3
  {
    const float4 w = *(const float4*)(wbuf + tid * 4);
    const int ch = tid >> 1, hs = (tid & 1) * 4;
    Wpt[hs + 0][ch] = w.x; Wpt[hs + 1][ch] = w.y;
    Wpt[hs + 2][ch] = w.z; Wpt[hs + 3][ch] = w.w;
  }
  __syncthreads();
  // stats (independent of dots)
  float s1a = 0.f, s2a = 0.f, s1b = 0.f, s2b = 0.f;
#pragma unroll
  for (int g = 0; g < 4; g++) {
    s1a += va[g].x + va[g].y + va[g].z + va[g].w;
    s2a += va[g].x * va[g].x + va[g].y * va[g].y + va[g].z * va[g].z + va[g].w * va[g].w;
    s1b += vb[g].x + vb[g].y + vb[g].z + vb[g].w;
    s2b += vb[g].x * vb[g].x + vb[g].y * vb[g].y + vb[g].z * vb[g].z + vb[g].w * vb[g].w;
  }
  // dots: d[h] = sum_c x[c]*Wp[c][h] over this lane's 16 channels
  float dA[8] = {0.f, 0.f, 0.f, 0.f, 0.f, 0.f, 0.f, 0.f};
  float dB[8] = {0.f, 0.f, 0.f, 0.f, 0.f, 0.f, 0.f, 0.f};
#pragma unroll
  for (int g = 0; g < 4; g++) {
    const int cb = g * 32 + hh * 4;
#pragma unroll
    for (int hd = 0; hd < 8; hd++) {
      const float4 w = *(const float4*)(&Wpt[hd][cb]);
      dA[hd] += va[g].x * w.x + va[g].y * w.y + va[g].z * w.z + va[g].w * w.w;
      dB[hd] += vb[g].x * w.x + vb[g].y * w.y + vb[g].z * w.z + vb[g].w * w.w;
    }
  }
  // stats butterfly over the 8 row-lanes (A and B chains interleaved for ILP)
#pragma unroll
  for (int m = 1; m < 8; m <<= 1) {
    s1a += __shfl_xor(s1a, m); s2a += __shfl_xor(s2a, m);
    s1b += __shfl_xor(s1b, m); s2b += __shfl_xor(s2b, m);
  }
  const float muA = s1a * (1.f / 128.f);
  const float rA = rsqrtf(s2a * (1.f / 128.f) - muA * muA + 1e-5f);
  const float muB = s1b * (1.f / 128.f);
  const float rB = rsqrtf(s2b * (1.f / 128.f) - muB * muB + 1e-5f);
  // reduce-scatter d over 8 lanes: 7 shuffles per row; lane ends with head h
  float a0, a1, a2, a3, b0, b1, b2, b3;
  {
    const bool hi = (hh & 1) != 0;
    a0 = (hi ? dA[4] : dA[0]) + __shfl_xor(hi ? dA[0] : dA[4], 1);
    a1 = (hi ? dA[5] : dA[1]) + __shfl_xor(hi ? dA[1] : dA[5], 1);
    a2 = (hi ? dA[6] : dA[2]) + __shfl_xor(hi ? dA[2] : dA[6], 1);
    a3 = (hi ? dA[7] : dA[3]) + __shfl_xor(hi ? dA[3] : dA[7], 1);
    b0 = (hi ? dB[4] : dB[0]) + __shfl_xor(hi ? dB[0] : dB[4], 1);
    b1 = (hi ? dB[5] : dB[1]) + __shfl_xor(hi ? dB[1] : dB[5], 1);
    b2 = (hi ? dB[6] : dB[2]) + __shfl_xor(hi ? dB[2] : dB[6], 1);
    b3 = (hi ? dB[7] : dB[3]) + __shfl_xor(hi ? dB[3] : dB[7], 1);
  }
  {
    const bool hi = (hh & 2) != 0;
    const float ta0 = __shfl_xor(hi ? a0 : a2, 2);
    const float ta1 = __shfl_xor(hi ? a1 : a3, 2);
    const float tb0 = __shfl_xor(hi ? b0 : b2, 2);
    const float tb1 = __shfl_xor(hi ? b1 : b3, 2);
    a0 = (hi ? a2 : a0) + ta0;
    a1 = (hi ? a3 : a1) + ta1;
    b0 = (hi ? b2 : b0) + tb0;
    b1 = (hi ? b3 : b1) + tb1;
  }
  {
    const bool hi = (hh & 4) != 0;
    const float ta = __shfl_xor(hi ? a0 : a1, 4);
    const float tb = __shfl_xor(hi ? b0 : b1, 4);
    a0 = (hi ? a1 : a0) + ta;
    b0 = (hi ? b1 : b0) + tb;
  }
  const float vA = rA * (a0 - muA * Ah) + Bh;
  const float vB = rB * (b0 - muB * Ah) + Bh;
  const int slA = ((ra & 15) << 2) | ((ra >> 4) & 3);
  const int kb = ra + 32;
  const int slB = ((kb & 15) << 2) | ((kb >> 4) & 3);
  plds[h * 64 + slA] = vA;
  plds[h * 64 + slB] = vB;
  __syncthreads();
  const int q = (pb * 64) >> 8, g = pb & 3;
  const int j = tid * 2;
  *(float2*)(biasB + (j >> 6) * 65536 + q * 256 + g * 64 + (j & 63)) =
      *(const float2*)(plds + j);
}

// ------ K4/K6: bf16 MFMA GEMM, A[M][256] @ Bt[N][256]^T, 128x128 tile,
//        global_load_lds(16B) staging into unpadded [128][32], BK=32 ------
template <bool OUT_BF16>
__global__ __launch_bounds__(256) void k_gemm(
    const u16* __restrict__ A, const u16* __restrict__ Bt,
    void* __restrict__ out, const float* __restrict__ obias, const int N) {
  __shared__ u16 As[128 * 32];
  __shared__ u16 Bs[128 * 32];
  const int tid = threadIdx.x, wid = tid >> 6, lane = tid & 63;
  const int quad = lane >> 4, l16 = lane & 15;
  const int wm = (wid >> 1) * 64, wn = (wid & 1) * 64;
  const int bm = blockIdx.x, bn = blockIdx.y;
  const int r0 = wid * 16 + (lane >> 2);
  const int kc = (lane & 3) * 8;
  const u16* gA0 = A + (size_t)(bm * 128 + r0) * 256 + kc;
  const u16* gA1 = A + (size_t)(bm * 128 + 64 + r0) * 256 + kc;
  const u16* gB0 = Bt + (size_t)(bn * 128 + r0) * 256 + kc;
  const u16* gB1 = Bt + (size_t)(bn * 128 + 64 + r0) * 256 + kc;
  u16* lA0 = As + wid * 512;
  u16* lA1 = As + 2048 + wid * 512;
  u16* lB0 = Bs + wid * 512;
  u16* lB1 = Bs + 2048 + wid * 512;
  f32x4 acc[4][4];
#pragma unroll
  for (int i = 0; i < 4; i++)
#pragma unroll
    for (int j = 0; j < 4; j++) acc[i][j] = f32x4{0.f, 0.f, 0.f, 0.f};
  for (int k0 = 0; k0 < 256; k0 += 32) {
    __syncthreads();
    load_lds16(gA0 + k0, lA0);
    load_lds16(gA1 + k0, lA1);
    load_lds16(gB0 + k0, lB0);
    load_lds16(gB1 + k0, lB1);
    __syncthreads();
    short8 af[4], bf[4];
#pragma unroll
    for (int i = 0; i < 4; i++)
      af[i] = *(const short8*)(As + (wm + i * 16 + l16) * 32 + quad * 8);
#pragma unroll
    for (int j = 0; j < 4; j++)
      bf[j] = *(const short8*)(Bs + (wn + j * 16 + l16) * 32 + quad * 8);
#pragma unroll
    for (int i = 0; i < 4; i++)
#pragma unroll
      for (int j = 0; j < 4; j++)
        acc[i][j] = __builtin_amdgcn_mfma_f32_16x16x32_bf16(af[i], bf[j], acc[i][j], 0, 0, 0);
  }
#pragma unroll
  for (int i = 0; i < 4; i++)
#pragma unroll
    for (int j = 0; j < 4; j++)
#pragma unroll
      for (int r = 0; r < 4; r++) {
        const int gm = bm * 128 + wm + i * 16 + quad * 4 + r;
        const int gn = bn * 128 + wn + j * 16 + l16;
        const float v = acc[i][j][r];
        if (OUT_BF16) ((u16*)out)[(size_t)gm * N + gn] = f2b(v);
        else ((float*)out)[(size_t)gm * N + gn] = v + obias[gn];
      }
}

// ---- K5: attention, block = (b, h, q-half): 512 thr = 8 waves x 16 q.
//      K in LDS (union-reused as P after softmax barrier); V^T permuted;
//      no max-subtraction (logits bounded; masked terms underflow to 0).
//      All exp inputs pre-scaled by log2e upstream -> raw exp2 here.
//      K LDS tile chunk-swizzled (chunk ^= (k>>1)&3) via per-lane source
//      pre-swizzle: kills the 8-way bank conflict on the QK ds_read_b128. ----
__global__ __launch_bounds__(512, 4) void k_attn(
    const u16* __restrict__ Y, const float* __restrict__ biasB,
    const float* __restrict__ mask, const float* __restrict__ gb,
    u16* __restrict__ Z) {
  __shared__ u16 KsPs[9216];   // Ks [256][32] (8192 u16), later per-wave Ps (8x1152)
  __shared__ u16 Vt[32 * 264]; // [c][slot], stride 264 = 8*33 (2-way-only aliasing)
  const int b = blockIdx.x, h = blockIdx.y, qh = blockIdx.z;
  const int tid = threadIdx.x, w = tid >> 6, lane = tid & 63;
  const int quad = lane >> 4, l16 = lane & 15;
  const int q0 = qh * 128 + w * 16;
  const u16* Yb = Y + (size_t)b * 256 * 1024;
  // ---- stage K [k][32c of head h] via async 16B loads (2 per wave).
  //      source chunk pre-swizzled so LDS(row, cc) = global(row, cc^((row>>1)&3)) ----
  {
    const int kr = w * 32 + (lane >> 2);
    const int kc = ((lane & 3) ^ ((lane >> 3) & 3)) * 8;  // (kr>>1)&3 == (lane>>3)&3
    load_lds16(Yb + (size_t)kr * 1024 + 256 + h * 32 + kc, KsPs + (w * 32) * 32);
    load_lds16(Yb + (size_t)(kr + 16) * 1024 + 256 + h * 32 + kc, KsPs + (w * 32 + 16) * 32);
  }
  // ---- stage V^T permuted: thread t -> slot t&255, c-chunk (t>>8)*16 ----
  {
    const int slot = tid & 255, c0 = (tid >> 8) * 16;
    const int kv = ((slot >> 6) << 6) + ((slot & 3) << 4) + ((slot >> 2) & 15);
    const u16* src = Yb + (size_t)kv * 1024 + 512 + h * 32 + c0;
    union { uint4 q[2]; u16 u[16]; } uu;
    uu.q[0] = *(const uint4*)(src);
    uu.q[1] = *(const uint4*)(src + 8);
#pragma unroll
    for (int j = 0; j < 16; j++) Vt[(c0 + j) * 264 + slot] = uu.u[j];
  }
  // ---- Q frag + mask (global, before barrier); mask pre-scaled by log2e ----
  const short8 aq = *(const short8*)(Yb + (size_t)(q0 + l16) * 1024 + h * 32 + quad * 8);
  float maskv[16];
#pragma unroll
  for (int ni = 0; ni < 16; ni++)
    maskv[ni] = 1.4426950409e9f * (mask[b * 256 + ni * 16 + l16] - 1.f);
  __syncthreads();  // K + V staging complete
  // ---- S = Q K^T : 16 MFMAs per wave (swizzled K chunk read) ----
  f32x4 S[16];
#pragma unroll
  for (int ni = 0; ni < 16; ni++) S[ni] = f32x4{0.f, 0.f, 0.f, 0.f};
#pragma unroll
  for (int ni = 0; ni < 16; ni++) {
    const short8 bk = *(const short8*)(
        KsPs + (ni * 16 + l16) * 32 + ((quad ^ ((l16 >> 1) & 3)) * 8));
    S[ni] = __builtin_amdgcn_mfma_f32_16x16x32_bf16(aq, bk, S[ni], 0, 0, 0);
  }
  // ---- + permuted pair bias + mask; softmax via raw exp2 (all log2e-scaled) ----
  float li[4];
#pragma unroll
  for (int r = 0; r < 4; r++) {
    const int qg = q0 + quad * 4 + r;
    const float* bb = biasB + (h << 16) + (qg << 8) + l16 * 4;
    const float4 b0 = *(const float4*)(bb);
    const float4 b1 = *(const float4*)(bb + 64);
    const float4 b2 = *(const float4*)(bb + 128);
    const float4 b3 = *(const float4*)(bb + 192);
    const float bv[16] = {b0.x, b0.y, b0.z, b0.w, b1.x, b1.y, b1.z, b1.w,
                          b2.x, b2.y, b2.z, b2.w, b3.x, b3.y, b3.z, b3.w};
    float l = 0.f;
#pragma unroll
    for (int ni = 0; ni < 16; ni++) {
      const float p = exp2f(S[ni][r] + bv[ni] + maskv[ni]);
      S[ni][r] = p;
      l += p;
    }
#pragma unroll
    for (int d = 1; d < 16; d <<= 1) l += __shfl_xor(l, d);
    li[r] = __builtin_amdgcn_rcpf(l);
  }
  __syncthreads();  // all K-reads done; Ks region becomes per-wave Ps
  // ---- P @ V in 4 k-quarters through per-wave LDS (wave-in-order DS) ----
  f32x4 O[2];
  O[0] = f32x4{0.f, 0.f, 0.f, 0.f};
  O[1] = f32x4{0.f, 0.f, 0.f, 0.f};
  u16* Pw = KsPs + w * 1152;  // [16 q][72]
#pragma unroll
  for (int Q = 0; Q < 4; Q++) {
#pragma unroll
    for (int r = 0; r < 4; r++) {
      uint2 wv;  // slots l16*4..+3 of row quad*4+r
      wv.x = cvtpk(S[Q * 4 + 0][r], S[Q * 4 + 1][r]);
      wv.y = cvtpk(S[Q * 4 + 2][r], S[Q * 4 + 3][r]);
      *(uint2*)(Pw + (quad * 4 + r) * 72 + l16 * 4) = wv;
    }
#pragma unroll
    for (int ks = 0; ks < 2; ks++) {
      const short8 ap = *(const short8*)(Pw + l16 * 72 + ks * 32 + quad * 8);
#pragma unroll
      for (int nj = 0; nj < 2; nj++) {
        const short8 bv = *(const short8*)(Vt + (nj * 16 + l16) * 264 + Q * 64 + ks * 32 + quad * 8);
        O[nj] = __builtin_amdgcn_mfma_f32_16x16x32_bf16(ap, bv, O[nj], 0, 0, 0);
      }
    }
  }
  // ---- epilogue: 1/l, gate sigmoid (log2e-folded), stage in Pw, 16B stores ----
  const float gs0 = gb[h * 32 + l16] * LOG2E;
  const float gs1 = gb[h * 32 + 16 + l16] * LOG2E;
#pragma unroll
  for (int nj = 0; nj < 2; nj++)
#pragma unroll
    for (int r = 0; r < 4; r++) {
      const int qg = q0 + quad * 4 + r;
      const int c = nj * 16 + l16;
      const float wa = O[nj][r] * li[r];
      const float gv = b2f(Yb[(size_t)qg * 1024 + 768 + h * 32 + c]) + (nj ? gs1 : gs0);
      const float gate = __builtin_amdgcn_rcpf(1.f + exp2f(-gv));
      Pw[(quad * 4 + r) * 40 + c] = f2b(wa * gate);
    }
  {
    const int qr = lane >> 2, cc = (lane & 3) * 8;
    const uint4 zv = *(const uint4*)(Pw + qr * 40 + cc);
    *(uint4*)(Z + ((size_t)(b * 256 + q0 + qr)) * 256 + h * 32 + cc) = zv;
  }
}

extern "C" void kernel_launch(void* const* d_in, const int* in_sizes, int n_in,
                              void* d_out, int out_size, void* d_ws, size_t ws_size,
                              hipStream_t stream) {
  const float* msa  = (const float*)d_in[0];
  const float* mask = (const float*)d_in[1];
  const float* pair = (const float*)d_in[2];
  const float* qns  = (const float*)d_in[3];
  const float* qnb  = (const float*)d_in[4];
  const float* pns  = (const float*)d_in[5];
  const float* pnb  = (const float*)d_in[6];
  const float* f2w  = (const float*)d_in[7];
  const float* qw   = (const float*)d_in[8];
  const float* kw   = (const float*)d_in[9];
  const float* vw   = (const float*)d_in[10];
  const float* gw   = (const float*)d_in[11];
  const float* gbp  = (const float*)d_in[12];
  const float* ow   = (const float*)d_in[13];
  const float* ob   = (const float*)d_in[14];
  float* out = (float*)d_out;
  char* ws = (char*)d_ws;
  u16*   xb    = (u16*)(ws);                  // 16777216 B
  u16*   Wt    = (u16*)(ws + 16777216);       //   524288 B
  u16*   OWt   = (u16*)(ws + 17301504);       //   131072 B
  float* biasB = (float*)(ws + 17432576);     //  2097152 B
  u16*   Y     = (u16*)(ws + 19529728);       // 67108864 B
  u16*   Z     = (u16*)(ws + 86638592);       // 16777216 B
  // Wp/A/B parked at the head of the Z region: written by k_tr, consumed by
  // k_pair, both complete before k_attn overwrites Z. No extra ws needed.
  float* wbuf  = (float*)(ws + 86638592);     //     4096 B (Wp[128][8])
  float* abuf  = wbuf + 1024;                 //       64 B (A[8], B[8])

  k_msa<<<1024, 256, 0, stream>>>(msa, qns, qnb, xb);
  k_tr<<<81, 256, 0, stream>>>(qw, kw, vw, gw, ow, pns, pnb, f2w,
                               Wt, OWt, wbuf, abuf);
  k_pair<<<1024, 256, 0, stream>>>(pair, wbuf, abuf, biasB);
  k_gemm<true><<<dim3(256, 8), 256, 0, stream>>>(xb, Wt, (void*)Y, nullptr, 1024);
  k_attn<<<dim3(128, 8, 2), 512, 0, stream>>>(Y, biasB, mask, gbp, Z);
  k_gemm<false><<<dim3(256, 2), 256, 0, stream>>>(Z, OWt, (void*)out, ob, 256);
}

// Round 5
// 237.244 us; speedup vs baseline: 1.0016x; 1.0016x over previous
//
#include <hip/hip_runtime.h>
#include <hip/hip_bf16.h>

typedef unsigned short u16;
typedef unsigned int u32;
typedef __attribute__((ext_vector_type(8))) short short8;
typedef __attribute__((ext_vector_type(4))) float f32x4;

// cheap RNE f32->bf16 (finite values only)
__device__ __forceinline__ u16 f2b(float f) {
  u32 u = __builtin_bit_cast(u32, f);
  u += 0x7fffu + ((u >> 16) & 1u);
  return (u16)(u >> 16);
}
// hardware packed f32x2 -> bf16x2 (lo = a, hi = b), RNE
__device__ __forceinline__ u32 cvtpk(float a, float b) {
  u32 r;
  asm("v_cvt_pk_bf16_f32 %0, %1, %2" : "=v"(r) : "v"(a), "v"(b));
  return r;
}
__device__ __forceinline__ float b2f(u16 u) {
  u32 x = ((u32)u) << 16;
  return __builtin_bit_cast(float, x);
}
__device__ __forceinline__ void load_lds16(const u16* g, u16* l) {
  __builtin_amdgcn_global_load_lds(
      (const __attribute__((address_space(1))) void*)(uintptr_t)g,
      (__attribute__((address_space(3))) void*)(u32)(uintptr_t)l, 16, 0, 0);
}

#define LOG2E 1.4426950408889634f

// k-slot permutation (64-granular): slot(k) = (k>>6)*64 + (k&15)*4 + ((k>>4)&3)

// ---- K_msa: LayerNorm(msa_act) -> bf16. 8 rows/wave, 8 independent float4
//      loads per thread (MLP is the lever; 32-VGPR regalloc serializing
//      loads was a 2.6x regression in round 1). ----
__global__ __launch_bounds__(256) void k_msa(
    const float* __restrict__ msa, const float* __restrict__ qns,
    const float* __restrict__ qnb, u16* __restrict__ xb) {
  const int tid = threadIdx.x, blk = blockIdx.x;
  const int wid = tid >> 6, lane = tid & 63;
  const int r = lane >> 3, c = lane & 7;
  const int row = blk * 32 + wid * 8 + r;
  const float* src = msa + (size_t)row * 256 + c * 4;
  float4 v[8];
#pragma unroll
  for (int it = 0; it < 8; it++)
    v[it] = *(const float4*)(src + it * 32);  // 8 independent 16B loads
  float s = 0.f, s2 = 0.f;
#pragma unroll
  for (int it = 0; it < 8; it++) {
    s += v[it].x + v[it].y + v[it].z + v[it].w;
    s2 += v[it].x * v[it].x + v[it].y * v[it].y + v[it].z * v[it].z + v[it].w * v[it].w;
  }
#pragma unroll
  for (int m = 1; m < 8; m <<= 1) { s += __shfl_xor(s, m); s2 += __shfl_xor(s2, m); }
  const float mu = s * (1.f / 256.f);
  const float rs = rsqrtf(s2 * (1.f / 256.f) - mu * mu + 1e-5f);
  u16* dst = xb + (size_t)row * 256 + c * 4;
#pragma unroll
  for (int it = 0; it < 8; it++) {
    const int c0 = it * 32 + c * 4;
    const float4 scv = *(const float4*)(qns + c0);
    const float4 biv = *(const float4*)(qnb + c0);
    uint2 o;
    o.x = cvtpk((v[it].x - mu) * rs * scv.x + biv.x, (v[it].y - mu) * rs * scv.y + biv.y);
    o.y = cvtpk((v[it].z - mu) * rs * scv.z + biv.z, (v[it].w - mu) * rs * scv.w + biv.w);
    *(uint2*)(dst + it * 32) = o;
  }
}

// ---- K_tr: weight transpose (blocks 0..79) + Wp/A/B precompute (block 80).
//      Wp[c][h] = LOG2E*pn_scale[c]*fw[c][h]; A[h] = sum_c Wp; B[h] = LOG2E*sum_c pnb*fw.
//      log2e pre-folded into Q weights (with 1/sqrt d), gate weights, and the
//      pair bias so k_attn can use raw v_exp (exp2) with no per-element mul. ----
__global__ __launch_bounds__(256) void k_tr(
    const float* __restrict__ qw, const float* __restrict__ kw,
    const float* __restrict__ vw, const float* __restrict__ gw,
    const float* __restrict__ ow, const float* __restrict__ pns,
    const float* __restrict__ pnb, const float* __restrict__ fw,
    u16* __restrict__ Wt, u16* __restrict__ OWt,
    float* __restrict__ wbuf, float* __restrict__ abuf) {
  const int tid = threadIdx.x;
  const int t = blockIdx.x;           // 0..80
  if (t == 80) {
    // ---- single wave: channels (lane, lane+64) ----
    if (tid >= 64) return;
    const int lane = tid;
    const float4 f0a = *(const float4*)(fw + lane * 8);
    const float4 f1a = *(const float4*)(fw + lane * 8 + 4);
    const float4 f0b = *(const float4*)(fw + (lane + 64) * 8);
    const float4 f1b = *(const float4*)(fw + (lane + 64) * 8 + 4);
    const float sa = pns[lane] * LOG2E, sb = pns[lane + 64] * LOG2E;
    const float ba = pnb[lane] * LOG2E, bb = pnb[lane + 64] * LOG2E;
    float4 w0a = {f0a.x * sa, f0a.y * sa, f0a.z * sa, f0a.w * sa};
    float4 w1a = {f1a.x * sa, f1a.y * sa, f1a.z * sa, f1a.w * sa};
    float4 w0b = {f0b.x * sb, f0b.y * sb, f0b.z * sb, f0b.w * sb};
    float4 w1b = {f1b.x * sb, f1b.y * sb, f1b.z * sb, f1b.w * sb};
    *(float4*)(wbuf + lane * 8) = w0a;
    *(float4*)(wbuf + lane * 8 + 4) = w1a;
    *(float4*)(wbuf + (lane + 64) * 8) = w0b;
    *(float4*)(wbuf + (lane + 64) * 8 + 4) = w1b;
    float pa[8] = {w0a.x + w0b.x, w0a.y + w0b.y, w0a.z + w0b.z, w0a.w + w0b.w,
                   w1a.x + w1b.x, w1a.y + w1b.y, w1a.z + w1b.z, w1a.w + w1b.w};
    float pb[8] = {ba * f0a.x + bb * f0b.x, ba * f0a.y + bb * f0b.y,
                   ba * f0a.z + bb * f0b.z, ba * f0a.w + bb * f0b.w,
                   ba * f1a.x + bb * f1b.x, ba * f1a.y + bb * f1b.y,
                   ba * f1a.z + bb * f1b.z, ba * f1a.w + bb * f1b.w};
#pragma unroll
    for (int m = 1; m < 64; m <<= 1) {
#pragma unroll
      for (int h = 0; h < 8; h++) {
        pa[h] += __shfl_xor(pa[h], m);
        pb[h] += __shfl_xor(pb[h], m);
      }
    }
    if (lane == 0) {
      *(float4*)(abuf)      = float4{pa[0], pa[1], pa[2], pa[3]};
      *(float4*)(abuf + 4)  = float4{pa[4], pa[5], pa[6], pa[7]};
      *(float4*)(abuf + 8)  = float4{pb[0], pb[1], pb[2], pb[3]};
      *(float4*)(abuf + 12) = float4{pb[4], pb[5], pb[6], pb[7]};
    }
    return;
  }
  __shared__ u16 tlds[64 * 66];
  const int proj = t >> 4, tile = t & 15;
  const int tr = (tile >> 2) * 64, tc = (tile & 3) * 64;
  const float* src = proj == 0 ? qw : proj == 1 ? kw : proj == 2 ? vw
                      : proj == 3 ? gw : ow;
  u16* dst = proj < 4 ? (Wt + proj * 65536) : OWt;
  // proj0: 1/sqrt(32) * log2e (folds softmax exp2 conversion into Q)
  // proj3: log2e (folds sigmoid exp2 conversion into gate)
  const float scale = proj == 0 ? 0.25503471881f
                      : proj == 3 ? LOG2E : 1.f;
  {
    const int rl = tid >> 2, cg = (tid & 3) * 16;
    const float* sp = src + (size_t)(tr + rl) * 256 + tc + cg;
    float4 a0 = *(const float4*)(sp);
    float4 a1 = *(const float4*)(sp + 4);
    float4 a2 = *(const float4*)(sp + 8);
    float4 a3 = *(const float4*)(sp + 12);
    float xs[16] = {a0.x, a0.y, a0.z, a0.w, a1.x, a1.y, a1.z, a1.w,
                    a2.x, a2.y, a2.z, a2.w, a3.x, a3.y, a3.z, a3.w};
#pragma unroll
    for (int j = 0; j < 16; j++)
      tlds[(cg + j) * 66 + rl] = f2b(xs[j] * scale);  // transposed store
  }
  __syncthreads();
  {
    const int cl = tid >> 2, ag = (tid & 3) * 16;
    union { uint4 q[2]; u16 u[16]; } uu;
#pragma unroll
    for (int j = 0; j < 16; j++) uu.u[j] = tlds[cl * 66 + ag + j];
    u16* dp = dst + (size_t)(tc + cl) * 256 + tr + ag;
    *(uint4*)(dp) = uu.q[0];
    *(uint4*)(dp + 8) = uu.q[1];
  }
}

// ---- K_pair: raw pair_act -> biasB[h][q][slot] via precomputed Wp/A/B.
//      ph[h] = r*(dot(x, Wp[:,h]) - mu*A[h]) + B[h]  (LN + log2e folded in). ----
__global__ __launch_bounds__(256) void k_pair(
    const float* __restrict__ pair, const float* __restrict__ wbuf,
    const float* __restrict__ abuf, float* __restrict__ biasB) {
  __shared__ float Wpt[8][132];
  __shared__ float plds[512];
  const int tid = threadIdx.x, pb = blockIdx.x;
  const int ra = tid >> 3, hh = tid & 7;
  const int R0 = pb * 64 + ra;                 // rows R0 and R0+32
  const float* p0 = pair + (size_t)R0 * 128 + hh * 4;
  const float* p1 = pair + (size_t)(R0 + 32) * 128 + hh * 4;
  float4 va[4], vb[4];
#pragma unroll
  for (int g = 0; g < 4; g++) va[g] = *(const float4*)(p0 + g * 32);
#pragma unroll
  for (int g = 0; g < 4; g++) vb[g] = *(const float4*)(p1 + g * 32);
  // reduce-scatter endpoint head for this lane:
  const int h = ((hh & 1) << 2) | (hh & 2) | ((hh >> 2) & 1);
  const float Ah = abuf[h], Bh = abuf[8 + h];
  // stage Wp transposed: thread t covers wbuf float4 t -> ch=t>>1, heads (t&1)*4..+3
  {
    const float4 w = *(const float4*)(wbuf + tid * 4);
    const int ch = tid >> 1, hs = (tid & 1) * 4;
    Wpt[hs + 0][ch] = w.x; Wpt[hs + 1][ch] = w.y;
    Wpt[hs + 2][ch] = w.z; Wpt[hs + 3][ch] = w.w;
  }
  __syncthreads();
  // stats (independent of dots)
  float s1a = 0.f, s2a = 0.f, s1b = 0.f, s2b = 0.f;
#pragma unroll
  for (int g = 0; g < 4; g++) {
    s1a += va[g].x + va[g].y + va[g].z + va[g].w;
    s2a += va[g].x * va[g].x + va[g].y * va[g].y + va[g].z * va[g].z + va[g].w * va[g].w;
    s1b += vb[g].x + vb[g].y + vb[g].z + vb[g].w;
    s2b += vb[g].x * vb[g].x + vb[g].y * vb[g].y + vb[g].z * vb[g].z + vb[g].w * vb[g].w;
  }
  // dots: d[h] = sum_c x[c]*Wp[c][h] over this lane's 16 channels
  float dA[8] = {0.f, 0.f, 0.f, 0.f, 0.f, 0.f, 0.f, 0.f};
  float dB[8] = {0.f, 0.f, 0.f, 0.f, 0.f, 0.f, 0.f, 0.f};
#pragma unroll
  for (int g = 0; g < 4; g++) {
    const int cb = g * 32 + hh * 4;
#pragma unroll
    for (int hd = 0; hd < 8; hd++) {
      const float4 w = *(const float4*)(&Wpt[hd][cb]);
      dA[hd] += va[g].x * w.x + va[g].y * w.y + va[g].z * w.z + va[g].w * w.w;
      dB[hd] += vb[g].x * w.x + vb[g].y * w.y + vb[g].z * w.z + vb[g].w * w.w;
    }
  }
  // stats butterfly over the 8 row-lanes (A and B chains interleaved for ILP)
#pragma unroll
  for (int m = 1; m < 8; m <<= 1) {
    s1a += __shfl_xor(s1a, m); s2a += __shfl_xor(s2a, m);
    s1b += __shfl_xor(s1b, m); s2b += __shfl_xor(s2b, m);
  }
  const float muA = s1a * (1.f / 128.f);
  const float rA = rsqrtf(s2a * (1.f / 128.f) - muA * muA + 1e-5f);
  const float muB = s1b * (1.f / 128.f);
  const float rB = rsqrtf(s2b * (1.f / 128.f) - muB * muB + 1e-5f);
  // reduce-scatter d over 8 lanes: 7 shuffles per row; lane ends with head h
  float a0, a1, a2, a3, b0, b1, b2, b3;
  {
    const bool hi = (hh & 1) != 0;
    a0 = (hi ? dA[4] : dA[0]) + __shfl_xor(hi ? dA[0] : dA[4], 1);
    a1 = (hi ? dA[5] : dA[1]) + __shfl_xor(hi ? dA[1] : dA[5], 1);
    a2 = (hi ? dA[6] : dA[2]) + __shfl_xor(hi ? dA[2] : dA[6], 1);
    a3 = (hi ? dA[7] : dA[3]) + __shfl_xor(hi ? dA[3] : dA[7], 1);
    b0 = (hi ? dB[4] : dB[0]) + __shfl_xor(hi ? dB[0] : dB[4], 1);
    b1 = (hi ? dB[5] : dB[1]) + __shfl_xor(hi ? dB[1] : dB[5], 1);
    b2 = (hi ? dB[6] : dB[2]) + __shfl_xor(hi ? dB[2] : dB[6], 1);
    b3 = (hi ? dB[7] : dB[3]) + __shfl_xor(hi ? dB[3] : dB[7], 1);
  }
  {
    const bool hi = (hh & 2) != 0;
    const float ta0 = __shfl_xor(hi ? a0 : a2, 2);
    const float ta1 = __shfl_xor(hi ? a1 : a3, 2);
    const float tb0 = __shfl_xor(hi ? b0 : b2, 2);
    const float tb1 = __shfl_xor(hi ? b1 : b3, 2);
    a0 = (hi ? a2 : a0) + ta0;
    a1 = (hi ? a3 : a1) + ta1;
    b0 = (hi ? b2 : b0) + tb0;
    b1 = (hi ? b3 : b1) + tb1;
  }
  {
    const bool hi = (hh & 4) != 0;
    const float ta = __shfl_xor(hi ? a0 : a1, 4);
    const float tb = __shfl_xor(hi ? b0 : b1, 4);
    a0 = (hi ? a1 : a0) + ta;
    b0 = (hi ? b1 : b0) + tb;
  }
  const float vA = rA * (a0 - muA * Ah) + Bh;
  const float vB = rB * (b0 - muB * Ah) + Bh;
  const int slA = ((ra & 15) << 2) | ((ra >> 4) & 3);
  const int kb = ra + 32;
  const int slB = ((kb & 15) << 2) | ((kb >> 4) & 3);
  plds[h * 64 + slA] = vA;
  plds[h * 64 + slB] = vB;
  __syncthreads();
  const int q = (pb * 64) >> 8, g = pb & 3;
  const int j = tid * 2;
  *(float2*)(biasB + (j >> 6) * 65536 + q * 256 + g * 64 + (j & 63)) =
      *(const float2*)(plds + j);
}

// ------ K4/K6: bf16 MFMA GEMM, A[M][256] @ Bt[N][256]^T, 128x128 tile,
//        global_load_lds(16B) staging into unpadded [128][32], BK=32 ------
template <bool OUT_BF16>
__global__ __launch_bounds__(256) void k_gemm(
    const u16* __restrict__ A, const u16* __restrict__ Bt,
    void* __restrict__ out, const float* __restrict__ obias, const int N) {
  __shared__ u16 As[128 * 32];
  __shared__ u16 Bs[128 * 32];
  const int tid = threadIdx.x, wid = tid >> 6, lane = tid & 63;
  const int quad = lane >> 4, l16 = lane & 15;
  const int wm = (wid >> 1) * 64, wn = (wid & 1) * 64;
  const int bm = blockIdx.x, bn = blockIdx.y;
  const int r0 = wid * 16 + (lane >> 2);
  const int kc = (lane & 3) * 8;
  const u16* gA0 = A + (size_t)(bm * 128 + r0) * 256 + kc;
  const u16* gA1 = A + (size_t)(bm * 128 + 64 + r0) * 256 + kc;
  const u16* gB0 = Bt + (size_t)(bn * 128 + r0) * 256 + kc;
  const u16* gB1 = Bt + (size_t)(bn * 128 + 64 + r0) * 256 + kc;
  u16* lA0 = As + wid * 512;
  u16* lA1 = As + 2048 + wid * 512;
  u16* lB0 = Bs + wid * 512;
  u16* lB1 = Bs + 2048 + wid * 512;
  f32x4 acc[4][4];
#pragma unroll
  for (int i = 0; i < 4; i++)
#pragma unroll
    for (int j = 0; j < 4; j++) acc[i][j] = f32x4{0.f, 0.f, 0.f, 0.f};
  for (int k0 = 0; k0 < 256; k0 += 32) {
    __syncthreads();
    load_lds16(gA0 + k0, lA0);
    load_lds16(gA1 + k0, lA1);
    load_lds16(gB0 + k0, lB0);
    load_lds16(gB1 + k0, lB1);
    __syncthreads();
    short8 af[4], bf[4];
#pragma unroll
    for (int i = 0; i < 4; i++)
      af[i] = *(const short8*)(As + (wm + i * 16 + l16) * 32 + quad * 8);
#pragma unroll
    for (int j = 0; j < 4; j++)
      bf[j] = *(const short8*)(Bs + (wn + j * 16 + l16) * 32 + quad * 8);
#pragma unroll
    for (int i = 0; i < 4; i++)
#pragma unroll
      for (int j = 0; j < 4; j++)
        acc[i][j] = __builtin_amdgcn_mfma_f32_16x16x32_bf16(af[i], bf[j], acc[i][j], 0, 0, 0);
  }
#pragma unroll
  for (int i = 0; i < 4; i++)
#pragma unroll
    for (int j = 0; j < 4; j++)
#pragma unroll
      for (int r = 0; r < 4; r++) {
        const int gm = bm * 128 + wm + i * 16 + quad * 4 + r;
        const int gn = bn * 128 + wn + j * 16 + l16;
        const float v = acc[i][j][r];
        if (OUT_BF16) ((u16*)out)[(size_t)gm * N + gn] = f2b(v);
        else ((float*)out)[(size_t)gm * N + gn] = v + obias[gn];
      }
}

// ---- K5: attention, block = (b, h, q-half): 512 thr = 8 waves x 16 q.
//      K in LDS (union-reused as P after softmax barrier); V^T permuted;
//      no max-subtraction (logits bounded; masked terms underflow to 0).
//      All exp inputs pre-scaled by log2e upstream -> raw exp2 here.
//      LINEAR K staging/read (round-4 source-swizzle caused an 81% HBM
//      traffic regression: FETCH 57->74MB, WRITE 16->60MB — reverted). ----
__global__ __launch_bounds__(512, 4) void k_attn(
    const u16* __restrict__ Y, const float* __restrict__ biasB,
    const float* __restrict__ mask, const float* __restrict__ gb,
    u16* __restrict__ Z) {
  __shared__ u16 KsPs[9216];   // Ks [256][32] (8192 u16), later per-wave Ps (8x1152)
  __shared__ u16 Vt[32 * 264]; // [c][slot], stride 264 = 8*33 (2-way-only aliasing)
  const int b = blockIdx.x, h = blockIdx.y, qh = blockIdx.z;
  const int tid = threadIdx.x, w = tid >> 6, lane = tid & 63;
  const int quad = lane >> 4, l16 = lane & 15;
  const int q0 = qh * 128 + w * 16;
  const u16* Yb = Y + (size_t)b * 256 * 1024;
  // ---- stage K [k][32c of head h] via async 16B loads (2 per wave) ----
  {
    const int kr = w * 32 + (lane >> 2), kc = (lane & 3) * 8;
    load_lds16(Yb + (size_t)kr * 1024 + 256 + h * 32 + kc, KsPs + (w * 32) * 32);
    load_lds16(Yb + (size_t)(kr + 16) * 1024 + 256 + h * 32 + kc, KsPs + (w * 32 + 16) * 32);
  }
  // ---- stage V^T permuted: thread t -> slot t&255, c-chunk (t>>8)*16 ----
  {
    const int slot = tid & 255, c0 = (tid >> 8) * 16;
    const int kv = ((slot >> 6) << 6) + ((slot & 3) << 4) + ((slot >> 2) & 15);
    const u16* src = Yb + (size_t)kv * 1024 + 512 + h * 32 + c0;
    union { uint4 q[2]; u16 u[16]; } uu;
    uu.q[0] = *(const uint4*)(src);
    uu.q[1] = *(const uint4*)(src + 8);
#pragma unroll
    for (int j = 0; j < 16; j++) Vt[(c0 + j) * 264 + slot] = uu.u[j];
  }
  // ---- Q frag + mask (global, before barrier); mask pre-scaled by log2e ----
  const short8 aq = *(const short8*)(Yb + (size_t)(q0 + l16) * 1024 + h * 32 + quad * 8);
  float maskv[16];
#pragma unroll
  for (int ni = 0; ni < 16; ni++)
    maskv[ni] = 1.4426950409e9f * (mask[b * 256 + ni * 16 + l16] - 1.f);
  __syncthreads();  // K + V staging complete
  // ---- S = Q K^T : 16 MFMAs per wave ----
  f32x4 S[16];
#pragma unroll
  for (int ni = 0; ni < 16; ni++) S[ni] = f32x4{0.f, 0.f, 0.f, 0.f};
#pragma unroll
  for (int ni = 0; ni < 16; ni++) {
    const short8 bk = *(const short8*)(KsPs + (ni * 16 + l16) * 32 + quad * 8);
    S[ni] = __builtin_amdgcn_mfma_f32_16x16x32_bf16(aq, bk, S[ni], 0, 0, 0);
  }
  // ---- + permuted pair bias + mask; softmax via raw exp2 (all log2e-scaled) ----
  float li[4];
#pragma unroll
  for (int r = 0; r < 4; r++) {
    const int qg = q0 + quad * 4 + r;
    const float* bb = biasB + (h << 16) + (qg << 8) + l16 * 4;
    const float4 b0 = *(const float4*)(bb);
    const float4 b1 = *(const float4*)(bb + 64);
    const float4 b2 = *(const float4*)(bb + 128);
    const float4 b3 = *(const float4*)(bb + 192);
    const float bv[16] = {b0.x, b0.y, b0.z, b0.w, b1.x, b1.y, b1.z, b1.w,
                          b2.x, b2.y, b2.z, b2.w, b3.x, b3.y, b3.z, b3.w};
    float l = 0.f;
#pragma unroll
    for (int ni = 0; ni < 16; ni++) {
      const float p = exp2f(S[ni][r] + bv[ni] + maskv[ni]);
      S[ni][r] = p;
      l += p;
    }
#pragma unroll
    for (int d = 1; d < 16; d <<= 1) l += __shfl_xor(l, d);
    li[r] = __builtin_amdgcn_rcpf(l);
  }
  __syncthreads();  // all K-reads done; Ks region becomes per-wave Ps
  // ---- P @ V in 4 k-quarters through per-wave LDS (wave-in-order DS) ----
  f32x4 O[2];
  O[0] = f32x4{0.f, 0.f, 0.f, 0.f};
  O[1] = f32x4{0.f, 0.f, 0.f, 0.f};
  u16* Pw = KsPs + w * 1152;  // [16 q][72]
#pragma unroll
  for (int Q = 0; Q < 4; Q++) {
#pragma unroll
    for (int r = 0; r < 4; r++) {
      uint2 wv;  // slots l16*4..+3 of row quad*4+r
      wv.x = cvtpk(S[Q * 4 + 0][r], S[Q * 4 + 1][r]);
      wv.y = cvtpk(S[Q * 4 + 2][r], S[Q * 4 + 3][r]);
      *(uint2*)(Pw + (quad * 4 + r) * 72 + l16 * 4) = wv;
    }
#pragma unroll
    for (int ks = 0; ks < 2; ks++) {
      const short8 ap = *(const short8*)(Pw + l16 * 72 + ks * 32 + quad * 8);
#pragma unroll
      for (int nj = 0; nj < 2; nj++) {
        const short8 bv = *(const short8*)(Vt + (nj * 16 + l16) * 264 + Q * 64 + ks * 32 + quad * 8);
        O[nj] = __builtin_amdgcn_mfma_f32_16x16x32_bf16(ap, bv, O[nj], 0, 0, 0);
      }
    }
  }
  // ---- epilogue: 1/l, gate sigmoid (log2e-folded), stage in Pw, 16B stores ----
  const float gs0 = gb[h * 32 + l16] * LOG2E;
  const float gs1 = gb[h * 32 + 16 + l16] * LOG2E;
#pragma unroll
  for (int nj = 0; nj < 2; nj++)
#pragma unroll
    for (int r = 0; r < 4; r++) {
      const int qg = q0 + quad * 4 + r;
      const int c = nj * 16 + l16;
      const float wa = O[nj][r] * li[r];
      const float gv = b2f(Yb[(size_t)qg * 1024 + 768 + h * 32 + c]) + (nj ? gs1 : gs0);
      const float gate = __builtin_amdgcn_rcpf(1.f + exp2f(-gv));
      Pw[(quad * 4 + r) * 40 + c] = f2b(wa * gate);
    }
  {
    const int qr = lane >> 2, cc = (lane & 3) * 8;
    const uint4 zv = *(const uint4*)(Pw + qr * 40 + cc);
    *(uint4*)(Z + ((size_t)(b * 256 + q0 + qr)) * 256 + h * 32 + cc) = zv;
  }
}

extern "C" void kernel_launch(void* const* d_in, const int* in_sizes, int n_in,
                              void* d_out, int out_size, void* d_ws, size_t ws_size,
                              hipStream_t stream) {
  const float* msa  = (const float*)d_in[0];
  const float* mask = (const float*)d_in[1];
  const float* pair = (const float*)d_in[2];
  const float* qns  = (const float*)d_in[3];
  const float* qnb  = (const float*)d_in[4];
  const float* pns  = (const float*)d_in[5];
  const float* pnb  = (const float*)d_in[6];
  const float* f2w  = (const float*)d_in[7];
  const float* qw   = (const float*)d_in[8];
  const float* kw   = (const float*)d_in[9];
  const float* vw   = (const float*)d_in[10];
  const float* gw   = (const float*)d_in[11];
  const float* gbp  = (const float*)d_in[12];
  const float* ow   = (const float*)d_in[13];
  const float* ob   = (const float*)d_in[14];
  float* out = (float*)d_out;
  char* ws = (char*)d_ws;
  u16*   xb    = (u16*)(ws);                  // 16777216 B
  u16*   Wt    = (u16*)(ws + 16777216);       //   524288 B
  u16*   OWt   = (u16*)(ws + 17301504);       //   131072 B
  float* biasB = (float*)(ws + 17432576);     //  2097152 B
  u16*   Y     = (u16*)(ws + 19529728);       // 67108864 B
  u16*   Z     = (u16*)(ws + 86638592);       // 16777216 B
  // Wp/A/B parked at the head of the Z region: written by k_tr, consumed by
  // k_pair, both complete before k_attn overwrites Z. No extra ws needed.
  float* wbuf  = (float*)(ws + 86638592);     //     4096 B (Wp[128][8])
  float* abuf  = wbuf + 1024;                 //       64 B (A[8], B[8])

  k_msa<<<1024, 256, 0, stream>>>(msa, qns, qnb, xb);
  k_tr<<<81, 256, 0, stream>>>(qw, kw, vw, gw, ow, pns, pnb, f2w,
                               Wt, OWt, wbuf, abuf);
  k_pair<<<1024, 256, 0, stream>>>(pair, wbuf, abuf, biasB);
  k_gemm<true><<<dim3(256, 8), 256, 0, stream>>>(xb, Wt, (void*)Y, nullptr, 1024);
  k_attn<<<dim3(128, 8, 2), 512, 0, stream>>>(Y, biasB, mask, gbp, Z);
  k_gemm<false><<<dim3(256, 2), 256, 0, stream>>>(Z, OWt, (void*)out, ob, 256);
}

// Round 6
// 229.032 us; speedup vs baseline: 1.0375x; 1.0359x over previous
//
#include <hip/hip_runtime.h>
#include <hip/hip_bf16.h>

typedef unsigned short u16;
typedef unsigned int u32;
typedef __attribute__((ext_vector_type(8))) short short8;
typedef __attribute__((ext_vector_type(4))) float f32x4;

// cheap RNE f32->bf16 (finite values only).
// NOTE: do NOT replace with inline-asm v_cvt_pk_bf16_f32 — measured 42%
// k_attn regression (r4/r5), matching learn_hip m240 (asm cvt_pk -37%).
__device__ __forceinline__ u16 f2b(float f) {
  u32 u = __builtin_bit_cast(u32, f);
  u += 0x7fffu + ((u >> 16) & 1u);
  return (u16)(u >> 16);
}
__device__ __forceinline__ u32 pkb(float a, float b) {
  u32 ua = __builtin_bit_cast(u32, a);
  u32 ub = __builtin_bit_cast(u32, b);
  ua += 0x7fffu + ((ua >> 16) & 1u);
  ub += 0x7fffu + ((ub >> 16) & 1u);
  return (ua >> 16) | (ub & 0xffff0000u);
}
__device__ __forceinline__ float b2f(u16 u) {
  u32 x = ((u32)u) << 16;
  return __builtin_bit_cast(float, x);
}
__device__ __forceinline__ void load_lds16(const u16* g, u16* l) {
  __builtin_amdgcn_global_load_lds(
      (const __attribute__((address_space(1))) void*)(uintptr_t)g,
      (__attribute__((address_space(3))) void*)(u32)(uintptr_t)l, 16, 0, 0);
}

#define LOG2E 1.4426950408889634f

// k-slot permutation (64-granular): slot(k) = (k>>6)*64 + (k&15)*4 + ((k>>4)&3)

// ---- K_msa: LayerNorm(msa_act) -> bf16. 8 rows/wave, 8 independent float4
//      loads per thread (MLP is the lever; 32-VGPR regalloc serializing
//      loads was a 2.6x regression in round 1). ----
__global__ __launch_bounds__(256) void k_msa(
    const float* __restrict__ msa, const float* __restrict__ qns,
    const float* __restrict__ qnb, u16* __restrict__ xb) {
  const int tid = threadIdx.x, blk = blockIdx.x;
  const int wid = tid >> 6, lane = tid & 63;
  const int r = lane >> 3, c = lane & 7;
  const int row = blk * 32 + wid * 8 + r;
  const float* src = msa + (size_t)row * 256 + c * 4;
  float4 v[8];
#pragma unroll
  for (int it = 0; it < 8; it++)
    v[it] = *(const float4*)(src + it * 32);  // 8 independent 16B loads
  float s = 0.f, s2 = 0.f;
#pragma unroll
  for (int it = 0; it < 8; it++) {
    s += v[it].x + v[it].y + v[it].z + v[it].w;
    s2 += v[it].x * v[it].x + v[it].y * v[it].y + v[it].z * v[it].z + v[it].w * v[it].w;
  }
#pragma unroll
  for (int m = 1; m < 8; m <<= 1) { s += __shfl_xor(s, m); s2 += __shfl_xor(s2, m); }
  const float mu = s * (1.f / 256.f);
  const float rs = rsqrtf(s2 * (1.f / 256.f) - mu * mu + 1e-5f);
  u16* dst = xb + (size_t)row * 256 + c * 4;
#pragma unroll
  for (int it = 0; it < 8; it++) {
    const int c0 = it * 32 + c * 4;
    const float4 scv = *(const float4*)(qns + c0);
    const float4 biv = *(const float4*)(qnb + c0);
    uint2 o;
    o.x = pkb((v[it].x - mu) * rs * scv.x + biv.x, (v[it].y - mu) * rs * scv.y + biv.y);
    o.y = pkb((v[it].z - mu) * rs * scv.z + biv.z, (v[it].w - mu) * rs * scv.w + biv.w);
    *(uint2*)(dst + it * 32) = o;
  }
}

// ---- K_tr: weight transpose (blocks 0..79) + Wp/A/B precompute (block 80).
//      Wp[c][h] = LOG2E*pn_scale[c]*fw[c][h]; A[h] = sum_c Wp; B[h] = LOG2E*sum_c pnb*fw.
//      log2e pre-folded into Q weights (with 1/sqrt d), gate weights, and the
//      pair bias so k_attn can use raw v_exp (exp2) with no per-element mul. ----
__global__ __launch_bounds__(256) void k_tr(
    const float* __restrict__ qw, const float* __restrict__ kw,
    const float* __restrict__ vw, const float* __restrict__ gw,
    const float* __restrict__ ow, const float* __restrict__ pns,
    const float* __restrict__ pnb, const float* __restrict__ fw,
    u16* __restrict__ Wt, u16* __restrict__ OWt,
    float* __restrict__ wbuf, float* __restrict__ abuf) {
  const int tid = threadIdx.x;
  const int t = blockIdx.x;           // 0..80
  if (t == 80) {
    // ---- single wave: channels (lane, lane+64) ----
    if (tid >= 64) return;
    const int lane = tid;
    const float4 f0a = *(const float4*)(fw + lane * 8);
    const float4 f1a = *(const float4*)(fw + lane * 8 + 4);
    const float4 f0b = *(const float4*)(fw + (lane + 64) * 8);
    const float4 f1b = *(const float4*)(fw + (lane + 64) * 8 + 4);
    const float sa = pns[lane] * LOG2E, sb = pns[lane + 64] * LOG2E;
    const float ba = pnb[lane] * LOG2E, bb = pnb[lane + 64] * LOG2E;
    float4 w0a = {f0a.x * sa, f0a.y * sa, f0a.z * sa, f0a.w * sa};
    float4 w1a = {f1a.x * sa, f1a.y * sa, f1a.z * sa, f1a.w * sa};
    float4 w0b = {f0b.x * sb, f0b.y * sb, f0b.z * sb, f0b.w * sb};
    float4 w1b = {f1b.x * sb, f1b.y * sb, f1b.z * sb, f1b.w * sb};
    *(float4*)(wbuf + lane * 8) = w0a;
    *(float4*)(wbuf + lane * 8 + 4) = w1a;
    *(float4*)(wbuf + (lane + 64) * 8) = w0b;
    *(float4*)(wbuf + (lane + 64) * 8 + 4) = w1b;
    float pa[8] = {w0a.x + w0b.x, w0a.y + w0b.y, w0a.z + w0b.z, w0a.w + w0b.w,
                   w1a.x + w1b.x, w1a.y + w1b.y, w1a.z + w1b.z, w1a.w + w1b.w};
    float pb[8] = {ba * f0a.x + bb * f0b.x, ba * f0a.y + bb * f0b.y,
                   ba * f0a.z + bb * f0b.z, ba * f0a.w + bb * f0b.w,
                   ba * f1a.x + bb * f1b.x, ba * f1a.y + bb * f1b.y,
                   ba * f1a.z + bb * f1b.z, ba * f1a.w + bb * f1b.w};
#pragma unroll
    for (int m = 1; m < 64; m <<= 1) {
#pragma unroll
      for (int h = 0; h < 8; h++) {
        pa[h] += __shfl_xor(pa[h], m);
        pb[h] += __shfl_xor(pb[h], m);
      }
    }
    if (lane == 0) {
      *(float4*)(abuf)      = float4{pa[0], pa[1], pa[2], pa[3]};
      *(float4*)(abuf + 4)  = float4{pa[4], pa[5], pa[6], pa[7]};
      *(float4*)(abuf + 8)  = float4{pb[0], pb[1], pb[2], pb[3]};
      *(float4*)(abuf + 12) = float4{pb[4], pb[5], pb[6], pb[7]};
    }
    return;
  }
  __shared__ u16 tlds[64 * 66];
  const int proj = t >> 4, tile = t & 15;
  const int tr = (tile >> 2) * 64, tc = (tile & 3) * 64;
  const float* src = proj == 0 ? qw : proj == 1 ? kw : proj == 2 ? vw
                      : proj == 3 ? gw : ow;
  u16* dst = proj < 4 ? (Wt + proj * 65536) : OWt;
  // proj0: 1/sqrt(32) * log2e (folds softmax exp2 conversion into Q)
  // proj3: log2e (folds sigmoid exp2 conversion into gate)
  const float scale = proj == 0 ? 0.25503471881f
                      : proj == 3 ? LOG2E : 1.f;
  {
    const int rl = tid >> 2, cg = (tid & 3) * 16;
    const float* sp = src + (size_t)(tr + rl) * 256 + tc + cg;
    float4 a0 = *(const float4*)(sp);
    float4 a1 = *(const float4*)(sp + 4);
    float4 a2 = *(const float4*)(sp + 8);
    float4 a3 = *(const float4*)(sp + 12);
    float xs[16] = {a0.x, a0.y, a0.z, a0.w, a1.x, a1.y, a1.z, a1.w,
                    a2.x, a2.y, a2.z, a2.w, a3.x, a3.y, a3.z, a3.w};
#pragma unroll
    for (int j = 0; j < 16; j++)
      tlds[(cg + j) * 66 + rl] = f2b(xs[j] * scale);  // transposed store
  }
  __syncthreads();
  {
    const int cl = tid >> 2, ag = (tid & 3) * 16;
    union { uint4 q[2]; u16 u[16]; } uu;
#pragma unroll
    for (int j = 0; j < 16; j++) uu.u[j] = tlds[cl * 66 + ag + j];
    u16* dp = dst + (size_t)(tc + cl) * 256 + tr + ag;
    *(uint4*)(dp) = uu.q[0];
    *(uint4*)(dp + 8) = uu.q[1];
  }
}

// ---- K_pair: raw pair_act -> biasB[h][q][slot] via precomputed Wp/A/B.
//      ph[h] = r*(dot(x, Wp[:,h]) - mu*A[h]) + B[h]  (LN + log2e folded in). ----
__global__ __launch_bounds__(256) void k_pair(
    const float* __restrict__ pair, const float* __restrict__ wbuf,
    const float* __restrict__ abuf, float* __restrict__ biasB) {
  __shared__ float Wpt[8][132];
  __shared__ float plds[512];
  const int tid = threadIdx.x, pb = blockIdx.x;
  const int ra = tid >> 3, hh = tid & 7;
  const int R0 = pb * 64 + ra;                 // rows R0 and R0+32
  const float* p0 = pair + (size_t)R0 * 128 + hh * 4;
  const float* p1 = pair + (size_t)(R0 + 32) * 128 + hh * 4;
  float4 va[4], vb[4];
#pragma unroll
  for (int g = 0; g < 4; g++) va[g] = *(const float4*)(p0 + g * 32);
#pragma unroll
  for (int g = 0; g < 4; g++) vb[g] = *(const float4*)(p1 + g * 32);
  // reduce-scatter endpoint head for this lane:
  const int h = ((hh & 1) << 2) | (hh & 2) | ((hh >> 2) & 1);
  const float Ah = abuf[h], Bh = abuf[8 + h];
  // stage Wp transposed: thread t covers wbuf float4 t -> ch=t>>1, heads (t&1)*4..+3
  {
    const float4 w = *(const float4*)(wbuf + tid * 4);
    const int ch = tid >> 1, hs = (tid & 1) * 4;
    Wpt[hs + 0][ch] = w.x; Wpt[hs + 1][ch] = w.y;
    Wpt[hs + 2][ch] = w.z; Wpt[hs + 3][ch] = w.w;
  }
  __syncthreads();
  // stats (independent of dots)
  float s1a = 0.f, s2a = 0.f, s1b = 0.f, s2b = 0.f;
#pragma unroll
  for (int g = 0; g < 4; g++) {
    s1a += va[g].x + va[g].y + va[g].z + va[g].w;
    s2a += va[g].x * va[g].x + va[g].y * va[g].y + va[g].z * va[g].z + va[g].w * va[g].w;
    s1b += vb[g].x + vb[g].y + vb[g].z + vb[g].w;
    s2b += vb[g].x * vb[g].x + vb[g].y * vb[g].y + vb[g].z * vb[g].z + vb[g].w * vb[g].w;
  }
  // dots: d[h] = sum_c x[c]*Wp[c][h] over this lane's 16 channels
  float dA[8] = {0.f, 0.f, 0.f, 0.f, 0.f, 0.f, 0.f, 0.f};
  float dB[8] = {0.f, 0.f, 0.f, 0.f, 0.f, 0.f, 0.f, 0.f};
#pragma unroll
  for (int g = 0; g < 4; g++) {
    const int cb = g * 32 + hh * 4;
#pragma unroll
    for (int hd = 0; hd < 8; hd++) {
      const float4 w = *(const float4*)(&Wpt[hd][cb]);
      dA[hd] += va[g].x * w.x + va[g].y * w.y + va[g].z * w.z + va[g].w * w.w;
      dB[hd] += vb[g].x * w.x + vb[g].y * w.y + vb[g].z * w.z + vb[g].w * w.w;
    }
  }
  // stats butterfly over the 8 row-lanes (A and B chains interleaved for ILP)
#pragma unroll
  for (int m = 1; m < 8; m <<= 1) {
    s1a += __shfl_xor(s1a, m); s2a += __shfl_xor(s2a, m);
    s1b += __shfl_xor(s1b, m); s2b += __shfl_xor(s2b, m);
  }
  const float muA = s1a * (1.f / 128.f);
  const float rA = rsqrtf(s2a * (1.f / 128.f) - muA * muA + 1e-5f);
  const float muB = s1b * (1.f / 128.f);
  const float rB = rsqrtf(s2b * (1.f / 128.f) - muB * muB + 1e-5f);
  // reduce-scatter d over 8 lanes: 7 shuffles per row; lane ends with head h
  float a0, a1, a2, a3, b0, b1, b2, b3;
  {
    const bool hi = (hh & 1) != 0;
    a0 = (hi ? dA[4] : dA[0]) + __shfl_xor(hi ? dA[0] : dA[4], 1);
    a1 = (hi ? dA[5] : dA[1]) + __shfl_xor(hi ? dA[1] : dA[5], 1);
    a2 = (hi ? dA[6] : dA[2]) + __shfl_xor(hi ? dA[2] : dA[6], 1);
    a3 = (hi ? dA[7] : dA[3]) + __shfl_xor(hi ? dA[3] : dA[7], 1);
    b0 = (hi ? dB[4] : dB[0]) + __shfl_xor(hi ? dB[0] : dB[4], 1);
    b1 = (hi ? dB[5] : dB[1]) + __shfl_xor(hi ? dB[1] : dB[5], 1);
    b2 = (hi ? dB[6] : dB[2]) + __shfl_xor(hi ? dB[2] : dB[6], 1);
    b3 = (hi ? dB[7] : dB[3]) + __shfl_xor(hi ? dB[3] : dB[7], 1);
  }
  {
    const bool hi = (hh & 2) != 0;
    const float ta0 = __shfl_xor(hi ? a0 : a2, 2);
    const float ta1 = __shfl_xor(hi ? a1 : a3, 2);
    const float tb0 = __shfl_xor(hi ? b0 : b2, 2);
    const float tb1 = __shfl_xor(hi ? b1 : b3, 2);
    a0 = (hi ? a2 : a0) + ta0;
    a1 = (hi ? a3 : a1) + ta1;
    b0 = (hi ? b2 : b0) + tb0;
    b1 = (hi ? b3 : b1) + tb1;
  }
  {
    const bool hi = (hh & 4) != 0;
    const float ta = __shfl_xor(hi ? a0 : a1, 4);
    const float tb = __shfl_xor(hi ? b0 : b1, 4);
    a0 = (hi ? a1 : a0) + ta;
    b0 = (hi ? b1 : b0) + tb;
  }
  const float vA = rA * (a0 - muA * Ah) + Bh;
  const float vB = rB * (b0 - muB * Ah) + Bh;
  const int slA = ((ra & 15) << 2) | ((ra >> 4) & 3);
  const int kb = ra + 32;
  const int slB = ((kb & 15) << 2) | ((kb >> 4) & 3);
  plds[h * 64 + slA] = vA;
  plds[h * 64 + slB] = vB;
  __syncthreads();
  const int q = (pb * 64) >> 8, g = pb & 3;
  const int j = tid * 2;
  *(float2*)(biasB + (j >> 6) * 65536 + q * 256 + g * 64 + (j & 63)) =
      *(const float2*)(plds + j);
}

// ------ K4/K6: bf16 MFMA GEMM, A[M][256] @ Bt[N][256]^T, 128x128 tile,
//        global_load_lds(16B) staging into unpadded [128][32], BK=32 ------
template <bool OUT_BF16>
__global__ __launch_bounds__(256) void k_gemm(
    const u16* __restrict__ A, const u16* __restrict__ Bt,
    void* __restrict__ out, const float* __restrict__ obias, const int N) {
  __shared__ u16 As[128 * 32];
  __shared__ u16 Bs[128 * 32];
  const int tid = threadIdx.x, wid = tid >> 6, lane = tid & 63;
  const int quad = lane >> 4, l16 = lane & 15;
  const int wm = (wid >> 1) * 64, wn = (wid & 1) * 64;
  const int bm = blockIdx.x, bn = blockIdx.y;
  const int r0 = wid * 16 + (lane >> 2);
  const int kc = (lane & 3) * 8;
  const u16* gA0 = A + (size_t)(bm * 128 + r0) * 256 + kc;
  const u16* gA1 = A + (size_t)(bm * 128 + 64 + r0) * 256 + kc;
  const u16* gB0 = Bt + (size_t)(bn * 128 + r0) * 256 + kc;
  const u16* gB1 = Bt + (size_t)(bn * 128 + 64 + r0) * 256 + kc;
  u16* lA0 = As + wid * 512;
  u16* lA1 = As + 2048 + wid * 512;
  u16* lB0 = Bs + wid * 512;
  u16* lB1 = Bs + 2048 + wid * 512;
  f32x4 acc[4][4];
#pragma unroll
  for (int i = 0; i < 4; i++)
#pragma unroll
    for (int j = 0; j < 4; j++) acc[i][j] = f32x4{0.f, 0.f, 0.f, 0.f};
  for (int k0 = 0; k0 < 256; k0 += 32) {
    __syncthreads();
    load_lds16(gA0 + k0, lA0);
    load_lds16(gA1 + k0, lA1);
    load_lds16(gB0 + k0, lB0);
    load_lds16(gB1 + k0, lB1);
    __syncthreads();
    short8 af[4], bf[4];
#pragma unroll
    for (int i = 0; i < 4; i++)
      af[i] = *(const short8*)(As + (wm + i * 16 + l16) * 32 + quad * 8);
#pragma unroll
    for (int j = 0; j < 4; j++)
      bf[j] = *(const short8*)(Bs + (wn + j * 16 + l16) * 32 + quad * 8);
#pragma unroll
    for (int i = 0; i < 4; i++)
#pragma unroll
      for (int j = 0; j < 4; j++)
        acc[i][j] = __builtin_amdgcn_mfma_f32_16x16x32_bf16(af[i], bf[j], acc[i][j], 0, 0, 0);
  }
#pragma unroll
  for (int i = 0; i < 4; i++)
#pragma unroll
    for (int j = 0; j < 4; j++)
#pragma unroll
      for (int r = 0; r < 4; r++) {
        const int gm = bm * 128 + wm + i * 16 + quad * 4 + r;
        const int gn = bn * 128 + wn + j * 16 + l16;
        const float v = acc[i][j][r];
        if (OUT_BF16) ((u16*)out)[(size_t)gm * N + gn] = f2b(v);
        else ((float*)out)[(size_t)gm * N + gn] = v + obias[gn];
      }
}

// ---- K5: attention, block = (b, h, q-half): 512 thr = 8 waves x 16 q.
//      K in LDS (union-reused as P after softmax barrier); V^T permuted;
//      no max-subtraction (logits bounded; masked terms underflow to 0).
//      All exp inputs pre-scaled by log2e upstream -> raw exp2 here.
//      Linear K staging; bf16 packing via scalar pkb/f2b (NOT asm cvt_pk). ----
__global__ __launch_bounds__(512, 4) void k_attn(
    const u16* __restrict__ Y, const float* __restrict__ biasB,
    const float* __restrict__ mask, const float* __restrict__ gb,
    u16* __restrict__ Z) {
  __shared__ u16 KsPs[9216];   // Ks [256][32] (8192 u16), later per-wave Ps (8x1152)
  __shared__ u16 Vt[32 * 264]; // [c][slot], stride 264 = 8*33 (2-way-only aliasing)
  const int b = blockIdx.x, h = blockIdx.y, qh = blockIdx.z;
  const int tid = threadIdx.x, w = tid >> 6, lane = tid & 63;
  const int quad = lane >> 4, l16 = lane & 15;
  const int q0 = qh * 128 + w * 16;
  const u16* Yb = Y + (size_t)b * 256 * 1024;
  // ---- stage K [k][32c of head h] via async 16B loads (2 per wave) ----
  {
    const int kr = w * 32 + (lane >> 2), kc = (lane & 3) * 8;
    load_lds16(Yb + (size_t)kr * 1024 + 256 + h * 32 + kc, KsPs + (w * 32) * 32);
    load_lds16(Yb + (size_t)(kr + 16) * 1024 + 256 + h * 32 + kc, KsPs + (w * 32 + 16) * 32);
  }
  // ---- stage V^T permuted: thread t -> slot t&255, c-chunk (t>>8)*16 ----
  {
    const int slot = tid & 255, c0 = (tid >> 8) * 16;
    const int kv = ((slot >> 6) << 6) + ((slot & 3) << 4) + ((slot >> 2) & 15);
    const u16* src = Yb + (size_t)kv * 1024 + 512 + h * 32 + c0;
    union { uint4 q[2]; u16 u[16]; } uu;
    uu.q[0] = *(const uint4*)(src);
    uu.q[1] = *(const uint4*)(src + 8);
#pragma unroll
    for (int j = 0; j < 16; j++) Vt[(c0 + j) * 264 + slot] = uu.u[j];
  }
  // ---- Q frag + mask (global, before barrier); mask pre-scaled by log2e ----
  const short8 aq = *(const short8*)(Yb + (size_t)(q0 + l16) * 1024 + h * 32 + quad * 8);
  float maskv[16];
#pragma unroll
  for (int ni = 0; ni < 16; ni++)
    maskv[ni] = 1.4426950409e9f * (mask[b * 256 + ni * 16 + l16] - 1.f);
  __syncthreads();  // K + V staging complete
  // ---- S = Q K^T : 16 MFMAs per wave ----
  f32x4 S[16];
#pragma unroll
  for (int ni = 0; ni < 16; ni++) S[ni] = f32x4{0.f, 0.f, 0.f, 0.f};
#pragma unroll
  for (int ni = 0; ni < 16; ni++) {
    const short8 bk = *(const short8*)(KsPs + (ni * 16 + l16) * 32 + quad * 8);
    S[ni] = __builtin_amdgcn_mfma_f32_16x16x32_bf16(aq, bk, S[ni], 0, 0, 0);
  }
  // ---- + permuted pair bias + mask; softmax via raw exp2 (all log2e-scaled) ----
  float li[4];
#pragma unroll
  for (int r = 0; r < 4; r++) {
    const int qg = q0 + quad * 4 + r;
    const float* bb = biasB + (h << 16) + (qg << 8) + l16 * 4;
    const float4 b0 = *(const float4*)(bb);
    const float4 b1 = *(const float4*)(bb + 64);
    const float4 b2 = *(const float4*)(bb + 128);
    const float4 b3 = *(const float4*)(bb + 192);
    const float bv[16] = {b0.x, b0.y, b0.z, b0.w, b1.x, b1.y, b1.z, b1.w,
                          b2.x, b2.y, b2.z, b2.w, b3.x, b3.y, b3.z, b3.w};
    float l = 0.f;
#pragma unroll
    for (int ni = 0; ni < 16; ni++) {
      const float p = exp2f(S[ni][r] + bv[ni] + maskv[ni]);
      S[ni][r] = p;
      l += p;
    }
#pragma unroll
    for (int d = 1; d < 16; d <<= 1) l += __shfl_xor(l, d);
    li[r] = __builtin_amdgcn_rcpf(l);
  }
  __syncthreads();  // all K-reads done; Ks region becomes per-wave Ps
  // ---- P @ V in 4 k-quarters through per-wave LDS (wave-in-order DS) ----
  f32x4 O[2];
  O[0] = f32x4{0.f, 0.f, 0.f, 0.f};
  O[1] = f32x4{0.f, 0.f, 0.f, 0.f};
  u16* Pw = KsPs + w * 1152;  // [16 q][72]
#pragma unroll
  for (int Q = 0; Q < 4; Q++) {
#pragma unroll
    for (int r = 0; r < 4; r++) {
      uint2 wv;  // slots l16*4..+3 of row quad*4+r
      wv.x = pkb(S[Q * 4 + 0][r], S[Q * 4 + 1][r]);
      wv.y = pkb(S[Q * 4 + 2][r], S[Q * 4 + 3][r]);
      *(uint2*)(Pw + (quad * 4 + r) * 72 + l16 * 4) = wv;
    }
#pragma unroll
    for (int ks = 0; ks < 2; ks++) {
      const short8 ap = *(const short8*)(Pw + l16 * 72 + ks * 32 + quad * 8);
#pragma unroll
      for (int nj = 0; nj < 2; nj++) {
        const short8 bv = *(const short8*)(Vt + (nj * 16 + l16) * 264 + Q * 64 + ks * 32 + quad * 8);
        O[nj] = __builtin_amdgcn_mfma_f32_16x16x32_bf16(ap, bv, O[nj], 0, 0, 0);
      }
    }
  }
  // ---- epilogue: 1/l, gate sigmoid (log2e-folded), stage in Pw, 16B stores ----
  const float gs0 = gb[h * 32 + l16] * LOG2E;
  const float gs1 = gb[h * 32 + 16 + l16] * LOG2E;
#pragma unroll
  for (int nj = 0; nj < 2; nj++)
#pragma unroll
    for (int r = 0; r < 4; r++) {
      const int qg = q0 + quad * 4 + r;
      const int c = nj * 16 + l16;
      const float wa = O[nj][r] * li[r];
      const float gv = b2f(Yb[(size_t)qg * 1024 + 768 + h * 32 + c]) + (nj ? gs1 : gs0);
      const float gate = __builtin_amdgcn_rcpf(1.f + exp2f(-gv));
      Pw[(quad * 4 + r) * 40 + c] = f2b(wa * gate);
    }
  {
    const int qr = lane >> 2, cc = (lane & 3) * 8;
    const uint4 zv = *(const uint4*)(Pw + qr * 40 + cc);
    *(uint4*)(Z + ((size_t)(b * 256 + q0 + qr)) * 256 + h * 32 + cc) = zv;
  }
}

extern "C" void kernel_launch(void* const* d_in, const int* in_sizes, int n_in,
                              void* d_out, int out_size, void* d_ws, size_t ws_size,
                              hipStream_t stream) {
  const float* msa  = (const float*)d_in[0];
  const float* mask = (const float*)d_in[1];
  const float* pair = (const float*)d_in[2];
  const float* qns  = (const float*)d_in[3];
  const float* qnb  = (const float*)d_in[4];
  const float* pns  = (const float*)d_in[5];
  const float* pnb  = (const float*)d_in[6];
  const float* f2w  = (const float*)d_in[7];
  const float* qw   = (const float*)d_in[8];
  const float* kw   = (const float*)d_in[9];
  const float* vw   = (const float*)d_in[10];
  const float* gw   = (const float*)d_in[11];
  const float* gbp  = (const float*)d_in[12];
  const float* ow   = (const float*)d_in[13];
  const float* ob   = (const float*)d_in[14];
  float* out = (float*)d_out;
  char* ws = (char*)d_ws;
  u16*   xb    = (u16*)(ws);                  // 16777216 B
  u16*   Wt    = (u16*)(ws + 16777216);       //   524288 B
  u16*   OWt   = (u16*)(ws + 17301504);       //   131072 B
  float* biasB = (float*)(ws + 17432576);     //  2097152 B
  u16*   Y     = (u16*)(ws + 19529728);       // 67108864 B
  u16*   Z     = (u16*)(ws + 86638592);       // 16777216 B
  // Wp/A/B parked at the head of the Z region: written by k_tr, consumed by
  // k_pair, both complete before k_attn overwrites Z. No extra ws needed.
  float* wbuf  = (float*)(ws + 86638592);     //     4096 B (Wp[128][8])
  float* abuf  = wbuf + 1024;                 //       64 B (A[8], B[8])

  k_msa<<<1024, 256, 0, stream>>>(msa, qns, qnb, xb);
  k_tr<<<81, 256, 0, stream>>>(qw, kw, vw, gw, ow, pns, pnb, f2w,
                               Wt, OWt, wbuf, abuf);
  k_pair<<<1024, 256, 0, stream>>>(pair, wbuf, abuf, biasB);
  k_gemm<true><<<dim3(256, 8), 256, 0, stream>>>(xb, Wt, (void*)Y, nullptr, 1024);
  k_attn<<<dim3(128, 8, 2), 512, 0, stream>>>(Y, biasB, mask, gbp, Z);
  k_gemm<false><<<dim3(256, 2), 256, 0, stream>>>(Z, OWt, (void*)out, ob, 256);
}

// Round 8
// 218.259 us; speedup vs baseline: 1.0887x; 1.0494x over previous
//
#include <hip/hip_runtime.h>
#include <hip/hip_bf16.h>

typedef unsigned short u16;
typedef unsigned int u32;
typedef __attribute__((ext_vector_type(8))) short short8;
typedef __attribute__((ext_vector_type(4))) float f32x4;

// cheap RNE f32->bf16 (finite values only).
// NOTE: do NOT replace with inline-asm v_cvt_pk_bf16_f32 — measured 42%
// k_attn regression (r4/r5 vs r6), matching learn_hip m240 (asm cvt_pk -37%).
__device__ __forceinline__ u16 f2b(float f) {
  u32 u = __builtin_bit_cast(u32, f);
  u += 0x7fffu + ((u >> 16) & 1u);
  return (u16)(u >> 16);
}
__device__ __forceinline__ u32 pkb(float a, float b) {
  u32 ua = __builtin_bit_cast(u32, a);
  u32 ub = __builtin_bit_cast(u32, b);
  ua += 0x7fffu + ((ua >> 16) & 1u);
  ub += 0x7fffu + ((ub >> 16) & 1u);
  return (ua >> 16) | (ub & 0xffff0000u);
}
__device__ __forceinline__ float b2f(u16 u) {
  u32 x = ((u32)u) << 16;
  return __builtin_bit_cast(float, x);
}
__device__ __forceinline__ void load_lds16(const u16* g, u16* l) {
  __builtin_amdgcn_global_load_lds(
      (const __attribute__((address_space(1))) void*)(uintptr_t)g,
      (__attribute__((address_space(3))) void*)(u32)(uintptr_t)l, 16, 0, 0);
}

#define LOG2E 1.4426950408889634f

// k-slot permutation (64-granular): slot(k) = (k>>6)*64 + (k&15)*4 + ((k>>4)&3)

// ---- K_msa: LayerNorm(msa_act) -> bf16. 8 rows/wave, 8 independent float4
//      loads per thread (MLP is the lever; 32-VGPR regalloc serializing
//      loads was a 2.6x regression in round 1). ----
__global__ __launch_bounds__(256) void k_msa(
    const float* __restrict__ msa, const float* __restrict__ qns,
    const float* __restrict__ qnb, u16* __restrict__ xb) {
  const int tid = threadIdx.x, blk = blockIdx.x;
  const int wid = tid >> 6, lane = tid & 63;
  const int r = lane >> 3, c = lane & 7;
  const int row = blk * 32 + wid * 8 + r;
  const float* src = msa + (size_t)row * 256 + c * 4;
  float4 v[8];
#pragma unroll
  for (int it = 0; it < 8; it++)
    v[it] = *(const float4*)(src + it * 32);  // 8 independent 16B loads
  float s = 0.f, s2 = 0.f;
#pragma unroll
  for (int it = 0; it < 8; it++) {
    s += v[it].x + v[it].y + v[it].z + v[it].w;
    s2 += v[it].x * v[it].x + v[it].y * v[it].y + v[it].z * v[it].z + v[it].w * v[it].w;
  }
#pragma unroll
  for (int m = 1; m < 8; m <<= 1) { s += __shfl_xor(s, m); s2 += __shfl_xor(s2, m); }
  const float mu = s * (1.f / 256.f);
  const float rs = rsqrtf(s2 * (1.f / 256.f) - mu * mu + 1e-5f);
  u16* dst = xb + (size_t)row * 256 + c * 4;
#pragma unroll
  for (int it = 0; it < 8; it++) {
    const int c0 = it * 32 + c * 4;
    const float4 scv = *(const float4*)(qns + c0);
    const float4 biv = *(const float4*)(qnb + c0);
    uint2 o;
    o.x = pkb((v[it].x - mu) * rs * scv.x + biv.x, (v[it].y - mu) * rs * scv.y + biv.y);
    o.y = pkb((v[it].z - mu) * rs * scv.z + biv.z, (v[it].w - mu) * rs * scv.w + biv.w);
    *(uint2*)(dst + it * 32) = o;
  }
}

// ---- K_tr: weight transpose (blocks 0..79) + Wp/A/B precompute (block 80).
//      Wp[c][h] = LOG2E*pn_scale[c]*fw[c][h]; A[h] = sum Wp; B[h] = LOG2E*sum pnb*fw.
//      log2e folded ONLY into the softmax-logit inputs (Q scale, pair bias,
//      mask const) so k_attn softmax uses raw v_exp_f32. Gate path unscaled. ----
__global__ __launch_bounds__(256) void k_tr(
    const float* __restrict__ qw, const float* __restrict__ kw,
    const float* __restrict__ vw, const float* __restrict__ gw,
    const float* __restrict__ ow, const float* __restrict__ pns,
    const float* __restrict__ pnb, const float* __restrict__ fw,
    u16* __restrict__ Wt, u16* __restrict__ OWt,
    float* __restrict__ wbuf, float* __restrict__ abuf) {
  const int tid = threadIdx.x;
  const int t = blockIdx.x;           // 0..80
  if (t == 80) {
    // ---- single wave: channels (lane, lane+64) ----
    if (tid >= 64) return;
    const int lane = tid;
    const float4 f0a = *(const float4*)(fw + lane * 8);
    const float4 f1a = *(const float4*)(fw + lane * 8 + 4);
    const float4 f0b = *(const float4*)(fw + (lane + 64) * 8);
    const float4 f1b = *(const float4*)(fw + (lane + 64) * 8 + 4);
    const float sa = pns[lane] * LOG2E, sb = pns[lane + 64] * LOG2E;
    const float ba = pnb[lane] * LOG2E, bb = pnb[lane + 64] * LOG2E;
    float4 w0a = {f0a.x * sa, f0a.y * sa, f0a.z * sa, f0a.w * sa};
    float4 w1a = {f1a.x * sa, f1a.y * sa, f1a.z * sa, f1a.w * sa};
    float4 w0b = {f0b.x * sb, f0b.y * sb, f0b.z * sb, f0b.w * sb};
    float4 w1b = {f1b.x * sb, f1b.y * sb, f1b.z * sb, f1b.w * sb};
    *(float4*)(wbuf + lane * 8) = w0a;
    *(float4*)(wbuf + lane * 8 + 4) = w1a;
    *(float4*)(wbuf + (lane + 64) * 8) = w0b;
    *(float4*)(wbuf + (lane + 64) * 8 + 4) = w1b;
    float pa[8] = {w0a.x + w0b.x, w0a.y + w0b.y, w0a.z + w0b.z, w0a.w + w0b.w,
                   w1a.x + w1b.x, w1a.y + w1b.y, w1a.z + w1b.z, w1a.w + w1b.w};
    float pb[8] = {ba * f0a.x + bb * f0b.x, ba * f0a.y + bb * f0b.y,
                   ba * f0a.z + bb * f0b.z, ba * f0a.w + bb * f0b.w,
                   ba * f1a.x + bb * f1b.x, ba * f1a.y + bb * f1b.y,
                   ba * f1a.z + bb * f1b.z, ba * f1a.w + bb * f1b.w};
#pragma unroll
    for (int m = 1; m < 64; m <<= 1) {
#pragma unroll
      for (int h = 0; h < 8; h++) {
        pa[h] += __shfl_xor(pa[h], m);
        pb[h] += __shfl_xor(pb[h], m);
      }
    }
    if (lane == 0) {
      *(float4*)(abuf)      = float4{pa[0], pa[1], pa[2], pa[3]};
      *(float4*)(abuf + 4)  = float4{pa[4], pa[5], pa[6], pa[7]};
      *(float4*)(abuf + 8)  = float4{pb[0], pb[1], pb[2], pb[3]};
      *(float4*)(abuf + 12) = float4{pb[4], pb[5], pb[6], pb[7]};
    }
    return;
  }
  __shared__ u16 tlds[64 * 66];
  const int proj = t >> 4, tile = t & 15;
  const int tr = (tile >> 2) * 64, tc = (tile & 3) * 64;
  const float* src = proj == 0 ? qw : proj == 1 ? kw : proj == 2 ? vw
                      : proj == 3 ? gw : ow;
  u16* dst = proj < 4 ? (Wt + proj * 65536) : OWt;
  // proj0: (1/sqrt 32)*log2e — folds the softmax exp2 conversion into Q
  const float scale = proj == 0 ? 0.25503471881f : 1.f;
  {
    const int rl = tid >> 2, cg = (tid & 3) * 16;
    const float* sp = src + (size_t)(tr + rl) * 256 + tc + cg;
    float4 a0 = *(const float4*)(sp);
    float4 a1 = *(const float4*)(sp + 4);
    float4 a2 = *(const float4*)(sp + 8);
    float4 a3 = *(const float4*)(sp + 12);
    float xs[16] = {a0.x, a0.y, a0.z, a0.w, a1.x, a1.y, a1.z, a1.w,
                    a2.x, a2.y, a2.z, a2.w, a3.x, a3.y, a3.z, a3.w};
#pragma unroll
    for (int j = 0; j < 16; j++)
      tlds[(cg + j) * 66 + rl] = f2b(xs[j] * scale);  // transposed store
  }
  __syncthreads();
  {
    const int cl = tid >> 2, ag = (tid & 3) * 16;
    union { uint4 q[2]; u16 u[16]; } uu;
#pragma unroll
    for (int j = 0; j < 16; j++) uu.u[j] = tlds[cl * 66 + ag + j];
    u16* dp = dst + (size_t)(tc + cl) * 256 + tr + ag;
    *(uint4*)(dp) = uu.q[0];
    *(uint4*)(dp + 8) = uu.q[1];
  }
}

// ---- K_pair: raw pair_act -> biasB[h][q][slot] via precomputed Wp/A/B.
//      ph[h] = r*(dot(x, Wp[:,h]) - mu*A[h]) + B[h]  (LN + log2e folded in). ----
__global__ __launch_bounds__(256) void k_pair(
    const float* __restrict__ pair, const float* __restrict__ wbuf,
    const float* __restrict__ abuf, float* __restrict__ biasB) {
  __shared__ float Wpt[8][132];
  __shared__ float plds[512];
  const int tid = threadIdx.x, pb = blockIdx.x;
  const int ra = tid >> 3, hh = tid & 7;
  const int R0 = pb * 64 + ra;                 // rows R0 and R0+32
  const float* p0 = pair + (size_t)R0 * 128 + hh * 4;
  const float* p1 = pair + (size_t)(R0 + 32) * 128 + hh * 4;
  float4 va[4], vb[4];
#pragma unroll
  for (int g = 0; g < 4; g++) va[g] = *(const float4*)(p0 + g * 32);
#pragma unroll
  for (int g = 0; g < 4; g++) vb[g] = *(const float4*)(p1 + g * 32);
  // reduce-scatter endpoint head for this lane:
  const int h = ((hh & 1) << 2) | (hh & 2) | ((hh >> 2) & 1);
  const float Ah = abuf[h], Bh = abuf[8 + h];
  // stage Wp transposed: thread t covers wbuf float4 t -> ch=t>>1, heads (t&1)*4..+3
  {
    const float4 w = *(const float4*)(wbuf + tid * 4);
    const int ch = tid >> 1, hs = (tid & 1) * 4;
    Wpt[hs + 0][ch] = w.x; Wpt[hs + 1][ch] = w.y;
    Wpt[hs + 2][ch] = w.z; Wpt[hs + 3][ch] = w.w;
  }
  __syncthreads();
  // stats (independent of dots)
  float s1a = 0.f, s2a = 0.f, s1b = 0.f, s2b = 0.f;
#pragma unroll
  for (int g = 0; g < 4; g++) {
    s1a += va[g].x + va[g].y + va[g].z + va[g].w;
    s2a += va[g].x * va[g].x + va[g].y * va[g].y + va[g].z * va[g].z + va[g].w * va[g].w;
    s1b += vb[g].x + vb[g].y + vb[g].z + vb[g].w;
    s2b += vb[g].x * vb[g].x + vb[g].y * vb[g].y + vb[g].z * vb[g].z + vb[g].w * vb[g].w;
  }
  // dots: d[h] = sum_c x[c]*Wp[c][h] over this lane's 16 channels
  float dA[8] = {0.f, 0.f, 0.f, 0.f, 0.f, 0.f, 0.f, 0.f};
  float dB[8] = {0.f, 0.f, 0.f, 0.f, 0.f, 0.f, 0.f, 0.f};
#pragma unroll
  for (int g = 0; g < 4; g++) {
    const int cb = g * 32 + hh * 4;
#pragma unroll
    for (int hd = 0; hd < 8; hd++) {
      const float4 w = *(const float4*)(&Wpt[hd][cb]);
      dA[hd] += va[g].x * w.x + va[g].y * w.y + va[g].z * w.z + va[g].w * w.w;
      dB[hd] += vb[g].x * w.x + vb[g].y * w.y + vb[g].z * w.z + vb[g].w * w.w;
    }
  }
  // stats butterfly over the 8 row-lanes (A and B chains interleaved for ILP)
#pragma unroll
  for (int m = 1; m < 8; m <<= 1) {
    s1a += __shfl_xor(s1a, m); s2a += __shfl_xor(s2a, m);
    s1b += __shfl_xor(s1b, m); s2b += __shfl_xor(s2b, m);
  }
  const float muA = s1a * (1.f / 128.f);
  const float rA = rsqrtf(s2a * (1.f / 128.f) - muA * muA + 1e-5f);
  const float muB = s1b * (1.f / 128.f);
  const float rB = rsqrtf(s2b * (1.f / 128.f) - muB * muB + 1e-5f);
  // reduce-scatter d over 8 lanes: 7 shuffles per row; lane ends with head h
  float a0, a1, a2, a3, b0, b1, b2, b3;
  {
    const bool hi = (hh & 1) != 0;
    a0 = (hi ? dA[4] : dA[0]) + __shfl_xor(hi ? dA[0] : dA[4], 1);
    a1 = (hi ? dA[5] : dA[1]) + __shfl_xor(hi ? dA[1] : dA[5], 1);
    a2 = (hi ? dA[6] : dA[2]) + __shfl_xor(hi ? dA[2] : dA[6], 1);
    a3 = (hi ? dA[7] : dA[3]) + __shfl_xor(hi ? dA[3] : dA[7], 1);
    b0 = (hi ? dB[4] : dB[0]) + __shfl_xor(hi ? dB[0] : dB[4], 1);
    b1 = (hi ? dB[5] : dB[1]) + __shfl_xor(hi ? dB[1] : dB[5], 1);
    b2 = (hi ? dB[6] : dB[2]) + __shfl_xor(hi ? dB[2] : dB[6], 1);
    b3 = (hi ? dB[7] : dB[3]) + __shfl_xor(hi ? dB[3] : dB[7], 1);
  }
  {
    const bool hi = (hh & 2) != 0;
    const float ta0 = __shfl_xor(hi ? a0 : a2, 2);
    const float ta1 = __shfl_xor(hi ? a1 : a3, 2);
    const float tb0 = __shfl_xor(hi ? b0 : b2, 2);
    const float tb1 = __shfl_xor(hi ? b1 : b3, 2);
    a0 = (hi ? a2 : a0) + ta0;
    a1 = (hi ? a3 : a1) + ta1;
    b0 = (hi ? b2 : b0) + tb0;
    b1 = (hi ? b3 : b1) + tb1;
  }
  {
    const bool hi = (hh & 4) != 0;
    const float ta = __shfl_xor(hi ? a0 : a1, 4);
    const float tb = __shfl_xor(hi ? b0 : b1, 4);
    a0 = (hi ? a1 : a0) + ta;
    b0 = (hi ? b1 : b0) + tb;
  }
  const float vA = rA * (a0 - muA * Ah) + Bh;
  const float vB = rB * (b0 - muB * Ah) + Bh;
  const int slA = ((ra & 15) << 2) | ((ra >> 4) & 3);
  const int kb = ra + 32;
  const int slB = ((kb & 15) << 2) | ((kb >> 4) & 3);
  plds[h * 64 + slA] = vA;
  plds[h * 64 + slB] = vB;
  __syncthreads();
  const int q = (pb * 64) >> 8, g = pb & 3;
  const int j = tid * 2;
  *(float2*)(biasB + (j >> 6) * 65536 + q * 256 + g * 64 + (j & 63)) =
      *(const float2*)(plds + j);
}

// ------ K4/K6: bf16 MFMA GEMM, A[M][256] @ Bt[N][256]^T, 128x128 tile,
//        global_load_lds(16B) staging into unpadded [128][32], BK=32 ------
template <bool OUT_BF16>
__global__ __launch_bounds__(256) void k_gemm(
    const u16* __restrict__ A, const u16* __restrict__ Bt,
    void* __restrict__ out, const float* __restrict__ obias, const int N) {
  __shared__ u16 As[128 * 32];
  __shared__ u16 Bs[128 * 32];
  const int tid = threadIdx.x, wid = tid >> 6, lane = tid & 63;
  const int quad = lane >> 4, l16 = lane & 15;
  const int wm = (wid >> 1) * 64, wn = (wid & 1) * 64;
  const int bm = blockIdx.x, bn = blockIdx.y;
  const int r0 = wid * 16 + (lane >> 2);
  const int kc = (lane & 3) * 8;
  const u16* gA0 = A + (size_t)(bm * 128 + r0) * 256 + kc;
  const u16* gA1 = A + (size_t)(bm * 128 + 64 + r0) * 256 + kc;
  const u16* gB0 = Bt + (size_t)(bn * 128 + r0) * 256 + kc;
  const u16* gB1 = Bt + (size_t)(bn * 128 + 64 + r0) * 256 + kc;
  u16* lA0 = As + wid * 512;
  u16* lA1 = As + 2048 + wid * 512;
  u16* lB0 = Bs + wid * 512;
  u16* lB1 = Bs + 2048 + wid * 512;
  f32x4 acc[4][4];
#pragma unroll
  for (int i = 0; i < 4; i++)
#pragma unroll
    for (int j = 0; j < 4; j++) acc[i][j] = f32x4{0.f, 0.f, 0.f, 0.f};
  for (int k0 = 0; k0 < 256; k0 += 32) {
    __syncthreads();
    load_lds16(gA0 + k0, lA0);
    load_lds16(gA1 + k0, lA1);
    load_lds16(gB0 + k0, lB0);
    load_lds16(gB1 + k0, lB1);
    __syncthreads();
    short8 af[4], bf[4];
#pragma unroll
    for (int i = 0; i < 4; i++)
      af[i] = *(const short8*)(As + (wm + i * 16 + l16) * 32 + quad * 8);
#pragma unroll
    for (int j = 0; j < 4; j++)
      bf[j] = *(const short8*)(Bs + (wn + j * 16 + l16) * 32 + quad * 8);
#pragma unroll
    for (int i = 0; i < 4; i++)
#pragma unroll
      for (int j = 0; j < 4; j++)
        acc[i][j] = __builtin_amdgcn_mfma_f32_16x16x32_bf16(af[i], bf[j], acc[i][j], 0, 0, 0);
  }
#pragma unroll
  for (int i = 0; i < 4; i++)
#pragma unroll
    for (int j = 0; j < 4; j++)
#pragma unroll
      for (int r = 0; r < 4; r++) {
        const int gm = bm * 128 + wm + i * 16 + quad * 4 + r;
        const int gn = bn * 128 + wn + j * 16 + l16;
        const float v = acc[i][j][r];
        if (OUT_BF16) ((u16*)out)[(size_t)gm * N + gn] = f2b(v);
        else ((float*)out)[(size_t)gm * N + gn] = v + obias[gn];
      }
}

// ---- K5: attention, block = (b, h, q-half): 512 thr = 8 waves x 16 q.
//      K in LDS (union-reused as P after softmax barrier); V^T permuted;
//      no max-subtraction (logits bounded; masked terms underflow to 0).
//      Softmax: raw v_exp_f32 via __builtin_amdgcn_exp2f — inputs pre-scaled
//      by log2e upstream (Q weights, pair bias, mask const). NOT libm exp2f
//      (r5/r6: OCML fixup path spilled ~30B/thread -> +31MB WRITE). ----
__global__ __launch_bounds__(512, 4) void k_attn(
    const u16* __restrict__ Y, const float* __restrict__ biasB,
    const float* __restrict__ mask, const float* __restrict__ gb,
    u16* __restrict__ Z) {
  __shared__ u16 KsPs[9216];   // Ks [256][32] (8192 u16), later per-wave Ps (8x1152)
  __shared__ u16 Vt[32 * 264]; // [c][slot], stride 264 = 8*33 (2-way-only aliasing)
  const int b = blockIdx.x, h = blockIdx.y, qh = blockIdx.z;
  const int tid = threadIdx.x, w = tid >> 6, lane = tid & 63;
  const int quad = lane >> 4, l16 = lane & 15;
  const int q0 = qh * 128 + w * 16;
  const u16* Yb = Y + (size_t)b * 256 * 1024;
  // ---- stage K [k][32c of head h] via async 16B loads (2 per wave) ----
  {
    const int kr = w * 32 + (lane >> 2), kc = (lane & 3) * 8;
    load_lds16(Yb + (size_t)kr * 1024 + 256 + h * 32 + kc, KsPs + (w * 32) * 32);
    load_lds16(Yb + (size_t)(kr + 16) * 1024 + 256 + h * 32 + kc, KsPs + (w * 32 + 16) * 32);
  }
  // ---- stage V^T permuted: thread t -> slot t&255, c-chunk (t>>8)*16 ----
  {
    const int slot = tid & 255, c0 = (tid >> 8) * 16;
    const int kv = ((slot >> 6) << 6) + ((slot & 3) << 4) + ((slot >> 2) & 15);
    const u16* src = Yb + (size_t)kv * 1024 + 512 + h * 32 + c0;
    union { uint4 q[2]; u16 u[16]; } uu;
    uu.q[0] = *(const uint4*)(src);
    uu.q[1] = *(const uint4*)(src + 8);
#pragma unroll
    for (int j = 0; j < 16; j++) Vt[(c0 + j) * 264 + slot] = uu.u[j];
  }
  // ---- Q frag + mask (global, before barrier); mask pre-scaled by log2e ----
  const short8 aq = *(const short8*)(Yb + (size_t)(q0 + l16) * 1024 + h * 32 + quad * 8);
  float maskv[16];
#pragma unroll
  for (int ni = 0; ni < 16; ni++)
    maskv[ni] = 1.4426950409e9f * (mask[b * 256 + ni * 16 + l16] - 1.f);
  __syncthreads();  // K + V staging complete
  // ---- S = Q K^T : 16 MFMAs per wave ----
  f32x4 S[16];
#pragma unroll
  for (int ni = 0; ni < 16; ni++) S[ni] = f32x4{0.f, 0.f, 0.f, 0.f};
#pragma unroll
  for (int ni = 0; ni < 16; ni++) {
    const short8 bk = *(const short8*)(KsPs + (ni * 16 + l16) * 32 + quad * 8);
    S[ni] = __builtin_amdgcn_mfma_f32_16x16x32_bf16(aq, bk, S[ni], 0, 0, 0);
  }
  // ---- + permuted pair bias + mask; softmax via raw v_exp_f32 ----
  float li[4];
#pragma unroll
  for (int r = 0; r < 4; r++) {
    const int qg = q0 + quad * 4 + r;
    const float* bb = biasB + (h << 16) + (qg << 8) + l16 * 4;
    const float4 b0 = *(const float4*)(bb);
    const float4 b1 = *(const float4*)(bb + 64);
    const float4 b2 = *(const float4*)(bb + 128);
    const float4 b3 = *(const float4*)(bb + 192);
    const float bv[16] = {b0.x, b0.y, b0.z, b0.w, b1.x, b1.y, b1.z, b1.w,
                          b2.x, b2.y, b2.z, b2.w, b3.x, b3.y, b3.z, b3.w};
    float l = 0.f;
#pragma unroll
    for (int ni = 0; ni < 16; ni++) {
      const float p = __builtin_amdgcn_exp2f(S[ni][r] + bv[ni] + maskv[ni]);
      S[ni][r] = p;
      l += p;
    }
#pragma unroll
    for (int d = 1; d < 16; d <<= 1) l += __shfl_xor(l, d);
    li[r] = __builtin_amdgcn_rcpf(l);
  }
  __syncthreads();  // all K-reads done; Ks region becomes per-wave Ps
  // ---- P @ V in 4 k-quarters through per-wave LDS (wave-in-order DS) ----
  f32x4 O[2];
  O[0] = f32x4{0.f, 0.f, 0.f, 0.f};
  O[1] = f32x4{0.f, 0.f, 0.f, 0.f};
  u16* Pw = KsPs + w * 1152;  // [16 q][72]
#pragma unroll
  for (int Q = 0; Q < 4; Q++) {
#pragma unroll
    for (int r = 0; r < 4; r++) {
      uint2 wv;  // slots l16*4..+3 of row quad*4+r
      wv.x = pkb(S[Q * 4 + 0][r], S[Q * 4 + 1][r]);
      wv.y = pkb(S[Q * 4 + 2][r], S[Q * 4 + 3][r]);
      *(uint2*)(Pw + (quad * 4 + r) * 72 + l16 * 4) = wv;
    }
#pragma unroll
    for (int ks = 0; ks < 2; ks++) {
      const short8 ap = *(const short8*)(Pw + l16 * 72 + ks * 32 + quad * 8);
#pragma unroll
      for (int nj = 0; nj < 2; nj++) {
        const short8 bv = *(const short8*)(Vt + (nj * 16 + l16) * 264 + Q * 64 + ks * 32 + quad * 8);
        O[nj] = __builtin_amdgcn_mfma_f32_16x16x32_bf16(ap, bv, O[nj], 0, 0, 0);
      }
    }
  }
  // ---- epilogue: 1/l, gate sigmoid, stage in Pw, coalesced 16B stores ----
  const float* gbh = gb + h * 32;
#pragma unroll
  for (int nj = 0; nj < 2; nj++)
#pragma unroll
    for (int r = 0; r < 4; r++) {
      const int qg = q0 + quad * 4 + r;
      const int c = nj * 16 + l16;
      const float wa = O[nj][r] * li[r];
      const float gv = b2f(Yb[(size_t)qg * 1024 + 768 + h * 32 + c]) + gbh[c];
      const float gate = __builtin_amdgcn_rcpf(1.f + __expf(-gv));
      Pw[(quad * 4 + r) * 40 + c] = f2b(wa * gate);
    }
  {
    const int qr = lane >> 2, cc = (lane & 3) * 8;
    const uint4 zv = *(const uint4*)(Pw + qr * 40 + cc);
    *(uint4*)(Z + ((size_t)(b * 256 + q0 + qr)) * 256 + h * 32 + cc) = zv;
  }
}

extern "C" void kernel_launch(void* const* d_in, const int* in_sizes, int n_in,
                              void* d_out, int out_size, void* d_ws, size_t ws_size,
                              hipStream_t stream) {
  const float* msa  = (const float*)d_in[0];
  const float* mask = (const float*)d_in[1];
  const float* pair = (const float*)d_in[2];
  const float* qns  = (const float*)d_in[3];
  const float* qnb  = (const float*)d_in[4];
  const float* pns  = (const float*)d_in[5];
  const float* pnb  = (const float*)d_in[6];
  const float* f2w  = (const float*)d_in[7];
  const float* qw   = (const float*)d_in[8];
  const float* kw   = (const float*)d_in[9];
  const float* vw   = (const float*)d_in[10];
  const float* gw   = (const float*)d_in[11];
  const float* gbp  = (const float*)d_in[12];
  const float* ow   = (const float*)d_in[13];
  const float* ob   = (const float*)d_in[14];
  float* out = (float*)d_out;
  char* ws = (char*)d_ws;
  u16*   xb    = (u16*)(ws);                  // 16777216 B
  u16*   Wt    = (u16*)(ws + 16777216);       //   524288 B
  u16*   OWt   = (u16*)(ws + 17301504);       //   131072 B
  float* biasB = (float*)(ws + 17432576);     //  2097152 B
  u16*   Y     = (u16*)(ws + 19529728);       // 67108864 B
  u16*   Z     = (u16*)(ws + 86638592);       // 16777216 B
  // Wp/A/B parked at the head of the Z region: written by k_tr, consumed by
  // k_pair, both complete before k_attn overwrites Z. No extra ws needed.
  float* wbuf  = (float*)(ws + 86638592);     //     4096 B (Wp[128][8])
  float* abuf  = wbuf + 1024;                 //       64 B (A[8], B[8])

  k_msa<<<1024, 256, 0, stream>>>(msa, qns, qnb, xb);
  k_tr<<<81, 256, 0, stream>>>(qw, kw, vw, gw, ow, pns, pnb, f2w,
                               Wt, OWt, wbuf, abuf);
  k_pair<<<1024, 256, 0, stream>>>(pair, wbuf, abuf, biasB);
  k_gemm<true><<<dim3(256, 8), 256, 0, stream>>>(xb, Wt, (void*)Y, nullptr, 1024);
  k_attn<<<dim3(128, 8, 2), 512, 0, stream>>>(Y, biasB, mask, gbp, Z);
  k_gemm<false><<<dim3(256, 2), 256, 0, stream>>>(Z, OWt, (void*)out, ob, 256);
}

// Round 9
// 212.120 us; speedup vs baseline: 1.1202x; 1.0289x over previous
//
#include <hip/hip_runtime.h>
#include <hip/hip_bf16.h>

typedef unsigned short u16;
typedef unsigned int u32;
typedef __attribute__((ext_vector_type(8))) short short8;
typedef __attribute__((ext_vector_type(4))) float f32x4;

// cheap RNE f32->bf16 (finite values only).
// NOTE: do NOT replace with inline-asm v_cvt_pk_bf16_f32 — measured 42%
// k_attn regression (r4/r5 vs r6), matching learn_hip m240 (asm cvt_pk -37%).
__device__ __forceinline__ u16 f2b(float f) {
  u32 u = __builtin_bit_cast(u32, f);
  u += 0x7fffu + ((u >> 16) & 1u);
  return (u16)(u >> 16);
}
__device__ __forceinline__ u32 pkb(float a, float b) {
  u32 ua = __builtin_bit_cast(u32, a);
  u32 ub = __builtin_bit_cast(u32, b);
  ua += 0x7fffu + ((ua >> 16) & 1u);
  ub += 0x7fffu + ((ub >> 16) & 1u);
  return (ua >> 16) | (ub & 0xffff0000u);
}
__device__ __forceinline__ float b2f(u16 u) {
  u32 x = ((u32)u) << 16;
  return __builtin_bit_cast(float, x);
}
__device__ __forceinline__ void load_lds16(const u16* g, u16* l) {
  __builtin_amdgcn_global_load_lds(
      (const __attribute__((address_space(1))) void*)(uintptr_t)g,
      (__attribute__((address_space(3))) void*)(u32)(uintptr_t)l, 16, 0, 0);
}

#define LOG2E 1.4426950408889634f

// k-slot permutation (64-granular): slot(k) = (k>>6)*64 + (k&15)*4 + ((k>>4)&3)

// ---- K_prep: ONE dispatch, three independent phases (6->4 launches total;
//      ~50-60us of the pipeline was inter-kernel overhead).
//   blk 0..1023    : LayerNorm(msa_act) -> bf16   (r8 k_msa body verbatim)
//   blk 1024..2047 : LN(pair)+feat2d -> biasB     (LN distributed into dot:
//                    xn = (x-mu)*rstd*pns+pnb per-lane, dot with Fpt=fw*log2e;
//                    algebraically == reference einsum * log2e; kills the
//                    wbuf/abuf cross-block dependency)
//   blk 2048..2127 : weight transpose             (r8 k_tr body, no block 80)
// Phase-ordered block layout (r0-proven safe); __launch_bounds__(256,2)
// permits <=128 VGPR to avert the r1 32-VGPR load-serialization clamp. ----
__global__ __launch_bounds__(256, 2) void k_prep(
    const float* __restrict__ msa, const float* __restrict__ qns,
    const float* __restrict__ qnb, const float* __restrict__ pair,
    const float* __restrict__ pns, const float* __restrict__ pnb,
    const float* __restrict__ fw, const float* __restrict__ qw,
    const float* __restrict__ kw, const float* __restrict__ vw,
    const float* __restrict__ gw, const float* __restrict__ ow,
    u16* __restrict__ xb, float* __restrict__ biasB,
    u16* __restrict__ Wt, u16* __restrict__ OWt) {
  __shared__ float Fpt[8][132];   // pair: fw^T * log2e
  __shared__ float plds[512];     // pair: head-major staging
  __shared__ u16 tlds[64 * 66];   // tr: transpose staging
  const int tid = threadIdx.x, blk = blockIdx.x;
  if (blk < 1024) {
    // ---- msa LN: 8 rows/wave, 8 independent float4 loads/thread ----
    const int wid = tid >> 6, lane = tid & 63;
    const int r = lane >> 3, c = lane & 7;
    const int row = blk * 32 + wid * 8 + r;
    const float* src = msa + (size_t)row * 256 + c * 4;
    float4 v[8];
#pragma unroll
    for (int it = 0; it < 8; it++)
      v[it] = *(const float4*)(src + it * 32);
    float s = 0.f, s2 = 0.f;
#pragma unroll
    for (int it = 0; it < 8; it++) {
      s += v[it].x + v[it].y + v[it].z + v[it].w;
      s2 += v[it].x * v[it].x + v[it].y * v[it].y + v[it].z * v[it].z + v[it].w * v[it].w;
    }
#pragma unroll
    for (int m = 1; m < 8; m <<= 1) { s += __shfl_xor(s, m); s2 += __shfl_xor(s2, m); }
    const float mu = s * (1.f / 256.f);
    const float rs = rsqrtf(s2 * (1.f / 256.f) - mu * mu + 1e-5f);
    u16* dst = xb + (size_t)row * 256 + c * 4;
#pragma unroll
    for (int it = 0; it < 8; it++) {
      const int c0 = it * 32 + c * 4;
      const float4 scv = *(const float4*)(qns + c0);
      const float4 biv = *(const float4*)(qnb + c0);
      uint2 o;
      o.x = pkb((v[it].x - mu) * rs * scv.x + biv.x, (v[it].y - mu) * rs * scv.y + biv.y);
      o.y = pkb((v[it].z - mu) * rs * scv.z + biv.z, (v[it].w - mu) * rs * scv.w + biv.w);
      *(uint2*)(dst + it * 32) = o;
    }
  } else if (blk < 2048) {
    // ---- pair LN + feat2d, self-contained (no precompute dependency) ----
    const int pb = blk - 1024;
    const int ra = tid >> 3, hh = tid & 7;
    const int R0 = pb * 64 + ra;               // rows R0 and R0+32
    const float* p0 = pair + (size_t)R0 * 128 + hh * 4;
    const float* p1 = pair + (size_t)(R0 + 32) * 128 + hh * 4;
    float4 va[4], vb[4];
#pragma unroll
    for (int g = 0; g < 4; g++) va[g] = *(const float4*)(p0 + g * 32);
#pragma unroll
    for (int g = 0; g < 4; g++) vb[g] = *(const float4*)(p1 + g * 32);
    // per-lane LN params for this lane's 16 channels (L1-resident)
    float4 sc[4], bi[4];
#pragma unroll
    for (int g = 0; g < 4; g++) {
      sc[g] = *(const float4*)(pns + g * 32 + hh * 4);
      bi[g] = *(const float4*)(pnb + g * 32 + hh * 4);
    }
    // reduce-scatter endpoint head for this lane:
    const int h = ((hh & 1) << 2) | (hh & 2) | ((hh >> 2) & 1);
    // stage fw^T * log2e: thread t -> ch=t>>1, heads (t&1)*4..+3
    {
      const float4 w = *(const float4*)(fw + tid * 4);
      const int ch = tid >> 1, hs = (tid & 1) * 4;
      Fpt[hs + 0][ch] = w.x * LOG2E; Fpt[hs + 1][ch] = w.y * LOG2E;
      Fpt[hs + 2][ch] = w.z * LOG2E; Fpt[hs + 3][ch] = w.w * LOG2E;
    }
    __syncthreads();
    // stats
    float s1a = 0.f, s2a = 0.f, s1b = 0.f, s2b = 0.f;
#pragma unroll
    for (int g = 0; g < 4; g++) {
      s1a += va[g].x + va[g].y + va[g].z + va[g].w;
      s2a += va[g].x * va[g].x + va[g].y * va[g].y + va[g].z * va[g].z + va[g].w * va[g].w;
      s1b += vb[g].x + vb[g].y + vb[g].z + vb[g].w;
      s2b += vb[g].x * vb[g].x + vb[g].y * vb[g].y + vb[g].z * vb[g].z + vb[g].w * vb[g].w;
    }
#pragma unroll
    for (int m = 1; m < 8; m <<= 1) {
      s1a += __shfl_xor(s1a, m); s2a += __shfl_xor(s2a, m);
      s1b += __shfl_xor(s1b, m); s2b += __shfl_xor(s2b, m);
    }
    const float muA = s1a * (1.f / 128.f);
    const float rA = rsqrtf(s2a * (1.f / 128.f) - muA * muA + 1e-5f);
    const float muB = s1b * (1.f / 128.f);
    const float rB = rsqrtf(s2b * (1.f / 128.f) - muB * muB + 1e-5f);
    // normalize in-lane, then dot with Fpt (LN fully distributed)
    float dA[8] = {0.f, 0.f, 0.f, 0.f, 0.f, 0.f, 0.f, 0.f};
    float dB[8] = {0.f, 0.f, 0.f, 0.f, 0.f, 0.f, 0.f, 0.f};
#pragma unroll
    for (int g = 0; g < 4; g++) {
      const int cb = g * 32 + hh * 4;
      float4 xa, xbv;
      xa.x = (va[g].x - muA) * rA * sc[g].x + bi[g].x;
      xa.y = (va[g].y - muA) * rA * sc[g].y + bi[g].y;
      xa.z = (va[g].z - muA) * rA * sc[g].z + bi[g].z;
      xa.w = (va[g].w - muA) * rA * sc[g].w + bi[g].w;
      xbv.x = (vb[g].x - muB) * rB * sc[g].x + bi[g].x;
      xbv.y = (vb[g].y - muB) * rB * sc[g].y + bi[g].y;
      xbv.z = (vb[g].z - muB) * rB * sc[g].z + bi[g].z;
      xbv.w = (vb[g].w - muB) * rB * sc[g].w + bi[g].w;
#pragma unroll
      for (int hd = 0; hd < 8; hd++) {
        const float4 w = *(const float4*)(&Fpt[hd][cb]);
        dA[hd] += xa.x * w.x + xa.y * w.y + xa.z * w.z + xa.w * w.w;
        dB[hd] += xbv.x * w.x + xbv.y * w.y + xbv.z * w.z + xbv.w * w.w;
      }
    }
    // reduce-scatter d over 8 lanes: 7 shuffles per row; lane ends with head h
    float a0, a1, a2, a3, b0, b1, b2, b3;
    {
      const bool hi = (hh & 1) != 0;
      a0 = (hi ? dA[4] : dA[0]) + __shfl_xor(hi ? dA[0] : dA[4], 1);
      a1 = (hi ? dA[5] : dA[1]) + __shfl_xor(hi ? dA[1] : dA[5], 1);
      a2 = (hi ? dA[6] : dA[2]) + __shfl_xor(hi ? dA[2] : dA[6], 1);
      a3 = (hi ? dA[7] : dA[3]) + __shfl_xor(hi ? dA[3] : dA[7], 1);
      b0 = (hi ? dB[4] : dB[0]) + __shfl_xor(hi ? dB[0] : dB[4], 1);
      b1 = (hi ? dB[5] : dB[1]) + __shfl_xor(hi ? dB[1] : dB[5], 1);
      b2 = (hi ? dB[6] : dB[2]) + __shfl_xor(hi ? dB[2] : dB[6], 1);
      b3 = (hi ? dB[7] : dB[3]) + __shfl_xor(hi ? dB[3] : dB[7], 1);
    }
    {
      const bool hi = (hh & 2) != 0;
      const float ta0 = __shfl_xor(hi ? a0 : a2, 2);
      const float ta1 = __shfl_xor(hi ? a1 : a3, 2);
      const float tb0 = __shfl_xor(hi ? b0 : b2, 2);
      const float tb1 = __shfl_xor(hi ? b1 : b3, 2);
      a0 = (hi ? a2 : a0) + ta0;
      a1 = (hi ? a3 : a1) + ta1;
      b0 = (hi ? b2 : b0) + tb0;
      b1 = (hi ? b3 : b1) + tb1;
    }
    {
      const bool hi = (hh & 4) != 0;
      const float ta = __shfl_xor(hi ? a0 : a1, 4);
      const float tb = __shfl_xor(hi ? b0 : b1, 4);
      a0 = (hi ? a1 : a0) + ta;
      b0 = (hi ? b1 : b0) + tb;
    }
    const int slA = ((ra & 15) << 2) | ((ra >> 4) & 3);
    const int kb = ra + 32;
    const int slB = ((kb & 15) << 2) | ((kb >> 4) & 3);
    plds[h * 64 + slA] = a0;
    plds[h * 64 + slB] = b0;
    __syncthreads();
    const int q = (pb * 64) >> 8, g = pb & 3;
    const int j = tid * 2;
    *(float2*)(biasB + (j >> 6) * 65536 + q * 256 + g * 64 + (j & 63)) =
        *(const float2*)(plds + j);
  } else {
    // ---- weight transpose via LDS: dst[col][row] = src[row][col] (bf16) ----
    const int t = blk - 2048;         // 0..79
    const int proj = t >> 4, tile = t & 15;
    const int tr = (tile >> 2) * 64, tc = (tile & 3) * 64;
    const float* src = proj == 0 ? qw : proj == 1 ? kw : proj == 2 ? vw
                        : proj == 3 ? gw : ow;
    u16* dst = proj < 4 ? (Wt + proj * 65536) : OWt;
    // proj0: (1/sqrt 32)*log2e — folds the softmax exp2 conversion into Q
    const float scale = proj == 0 ? 0.25503471881f : 1.f;
    {
      const int rl = tid >> 2, cg = (tid & 3) * 16;
      const float* sp = src + (size_t)(tr + rl) * 256 + tc + cg;
      float4 a0 = *(const float4*)(sp);
      float4 a1 = *(const float4*)(sp + 4);
      float4 a2 = *(const float4*)(sp + 8);
      float4 a3 = *(const float4*)(sp + 12);
      float xs[16] = {a0.x, a0.y, a0.z, a0.w, a1.x, a1.y, a1.z, a1.w,
                      a2.x, a2.y, a2.z, a2.w, a3.x, a3.y, a3.z, a3.w};
#pragma unroll
      for (int j = 0; j < 16; j++)
        tlds[(cg + j) * 66 + rl] = f2b(xs[j] * scale);  // transposed store
    }
    __syncthreads();
    {
      const int cl = tid >> 2, ag = (tid & 3) * 16;
      union { uint4 q[2]; u16 u[16]; } uu;
#pragma unroll
      for (int j = 0; j < 16; j++) uu.u[j] = tlds[cl * 66 + ag + j];
      u16* dp = dst + (size_t)(tc + cl) * 256 + tr + ag;
      *(uint4*)(dp) = uu.q[0];
      *(uint4*)(dp + 8) = uu.q[1];
    }
  }
}

// ------ K4/K6: bf16 MFMA GEMM, A[M][256] @ Bt[N][256]^T, 128x128 tile,
//        global_load_lds(16B) staging into unpadded [128][32], BK=32 ------
template <bool OUT_BF16>
__global__ __launch_bounds__(256) void k_gemm(
    const u16* __restrict__ A, const u16* __restrict__ Bt,
    void* __restrict__ out, const float* __restrict__ obias, const int N) {
  __shared__ u16 As[128 * 32];
  __shared__ u16 Bs[128 * 32];
  const int tid = threadIdx.x, wid = tid >> 6, lane = tid & 63;
  const int quad = lane >> 4, l16 = lane & 15;
  const int wm = (wid >> 1) * 64, wn = (wid & 1) * 64;
  const int bm = blockIdx.x, bn = blockIdx.y;
  const int r0 = wid * 16 + (lane >> 2);
  const int kc = (lane & 3) * 8;
  const u16* gA0 = A + (size_t)(bm * 128 + r0) * 256 + kc;
  const u16* gA1 = A + (size_t)(bm * 128 + 64 + r0) * 256 + kc;
  const u16* gB0 = Bt + (size_t)(bn * 128 + r0) * 256 + kc;
  const u16* gB1 = Bt + (size_t)(bn * 128 + 64 + r0) * 256 + kc;
  u16* lA0 = As + wid * 512;
  u16* lA1 = As + 2048 + wid * 512;
  u16* lB0 = Bs + wid * 512;
  u16* lB1 = Bs + 2048 + wid * 512;
  f32x4 acc[4][4];
#pragma unroll
  for (int i = 0; i < 4; i++)
#pragma unroll
    for (int j = 0; j < 4; j++) acc[i][j] = f32x4{0.f, 0.f, 0.f, 0.f};
  for (int k0 = 0; k0 < 256; k0 += 32) {
    __syncthreads();
    load_lds16(gA0 + k0, lA0);
    load_lds16(gA1 + k0, lA1);
    load_lds16(gB0 + k0, lB0);
    load_lds16(gB1 + k0, lB1);
    __syncthreads();
    short8 af[4], bf[4];
#pragma unroll
    for (int i = 0; i < 4; i++)
      af[i] = *(const short8*)(As + (wm + i * 16 + l16) * 32 + quad * 8);
#pragma unroll
    for (int j = 0; j < 4; j++)
      bf[j] = *(const short8*)(Bs + (wn + j * 16 + l16) * 32 + quad * 8);
#pragma unroll
    for (int i = 0; i < 4; i++)
#pragma unroll
      for (int j = 0; j < 4; j++)
        acc[i][j] = __builtin_amdgcn_mfma_f32_16x16x32_bf16(af[i], bf[j], acc[i][j], 0, 0, 0);
  }
#pragma unroll
  for (int i = 0; i < 4; i++)
#pragma unroll
    for (int j = 0; j < 4; j++)
#pragma unroll
      for (int r = 0; r < 4; r++) {
        const int gm = bm * 128 + wm + i * 16 + quad * 4 + r;
        const int gn = bn * 128 + wn + j * 16 + l16;
        const float v = acc[i][j][r];
        if (OUT_BF16) ((u16*)out)[(size_t)gm * N + gn] = f2b(v);
        else ((float*)out)[(size_t)gm * N + gn] = v + obias[gn];
      }
}

// ---- K5: attention, block = (b, h, q-half): 512 thr = 8 waves x 16 q.
//      K in LDS (union-reused as P after softmax barrier); V^T permuted;
//      no max-subtraction (logits bounded; masked terms underflow to 0).
//      Softmax: raw v_exp_f32 via __builtin_amdgcn_exp2f — inputs pre-scaled
//      by log2e upstream (Q weights, pair bias, mask const). NOT libm exp2f
//      (r5/r6: OCML fixup path cost ~10us + 31MB scratch WRITE). ----
__global__ __launch_bounds__(512, 4) void k_attn(
    const u16* __restrict__ Y, const float* __restrict__ biasB,
    const float* __restrict__ mask, const float* __restrict__ gb,
    u16* __restrict__ Z) {
  __shared__ u16 KsPs[9216];   // Ks [256][32] (8192 u16), later per-wave Ps (8x1152)
  __shared__ u16 Vt[32 * 264]; // [c][slot], stride 264 = 8*33 (2-way-only aliasing)
  const int b = blockIdx.x, h = blockIdx.y, qh = blockIdx.z;
  const int tid = threadIdx.x, w = tid >> 6, lane = tid & 63;
  const int quad = lane >> 4, l16 = lane & 15;
  const int q0 = qh * 128 + w * 16;
  const u16* Yb = Y + (size_t)b * 256 * 1024;
  // ---- stage K [k][32c of head h] via async 16B loads (2 per wave) ----
  {
    const int kr = w * 32 + (lane >> 2), kc = (lane & 3) * 8;
    load_lds16(Yb + (size_t)kr * 1024 + 256 + h * 32 + kc, KsPs + (w * 32) * 32);
    load_lds16(Yb + (size_t)(kr + 16) * 1024 + 256 + h * 32 + kc, KsPs + (w * 32 + 16) * 32);
  }
  // ---- stage V^T permuted: thread t -> slot t&255, c-chunk (t>>8)*16 ----
  {
    const int slot = tid & 255, c0 = (tid >> 8) * 16;
    const int kv = ((slot >> 6) << 6) + ((slot & 3) << 4) + ((slot >> 2) & 15);
    const u16* src = Yb + (size_t)kv * 1024 + 512 + h * 32 + c0;
    union { uint4 q[2]; u16 u[16]; } uu;
    uu.q[0] = *(const uint4*)(src);
    uu.q[1] = *(const uint4*)(src + 8);
#pragma unroll
    for (int j = 0; j < 16; j++) Vt[(c0 + j) * 264 + slot] = uu.u[j];
  }
  // ---- Q frag + mask (global, before barrier); mask pre-scaled by log2e ----
  const short8 aq = *(const short8*)(Yb + (size_t)(q0 + l16) * 1024 + h * 32 + quad * 8);
  float maskv[16];
#pragma unroll
  for (int ni = 0; ni < 16; ni++)
    maskv[ni] = 1.4426950409e9f * (mask[b * 256 + ni * 16 + l16] - 1.f);
  __syncthreads();  // K + V staging complete
  // ---- S = Q K^T : 16 MFMAs per wave ----
  f32x4 S[16];
#pragma unroll
  for (int ni = 0; ni < 16; ni++) S[ni] = f32x4{0.f, 0.f, 0.f, 0.f};
#pragma unroll
  for (int ni = 0; ni < 16; ni++) {
    const short8 bk = *(const short8*)(KsPs + (ni * 16 + l16) * 32 + quad * 8);
    S[ni] = __builtin_amdgcn_mfma_f32_16x16x32_bf16(aq, bk, S[ni], 0, 0, 0);
  }
  // ---- + permuted pair bias + mask; softmax via raw v_exp_f32 ----
  float li[4];
#pragma unroll
  for (int r = 0; r < 4; r++) {
    const int qg = q0 + quad * 4 + r;
    const float* bb = biasB + (h << 16) + (qg << 8) + l16 * 4;
    const float4 b0 = *(const float4*)(bb);
    const float4 b1 = *(const float4*)(bb + 64);
    const float4 b2 = *(const float4*)(bb + 128);
    const float4 b3 = *(const float4*)(bb + 192);
    const float bv[16] = {b0.x, b0.y, b0.z, b0.w, b1.x, b1.y, b1.z, b1.w,
                          b2.x, b2.y, b2.z, b2.w, b3.x, b3.y, b3.z, b3.w};
    float l = 0.f;
#pragma unroll
    for (int ni = 0; ni < 16; ni++) {
      const float p = __builtin_amdgcn_exp2f(S[ni][r] + bv[ni] + maskv[ni]);
      S[ni][r] = p;
      l += p;
    }
#pragma unroll
    for (int d = 1; d < 16; d <<= 1) l += __shfl_xor(l, d);
    li[r] = __builtin_amdgcn_rcpf(l);
  }
  __syncthreads();  // all K-reads done; Ks region becomes per-wave Ps
  // ---- P @ V in 4 k-quarters through per-wave LDS (wave-in-order DS) ----
  f32x4 O[2];
  O[0] = f32x4{0.f, 0.f, 0.f, 0.f};
  O[1] = f32x4{0.f, 0.f, 0.f, 0.f};
  u16* Pw = KsPs + w * 1152;  // [16 q][72]
#pragma unroll
  for (int Q = 0; Q < 4; Q++) {
#pragma unroll
    for (int r = 0; r < 4; r++) {
      uint2 wv;  // slots l16*4..+3 of row quad*4+r
      wv.x = pkb(S[Q * 4 + 0][r], S[Q * 4 + 1][r]);
      wv.y = pkb(S[Q * 4 + 2][r], S[Q * 4 + 3][r]);
      *(uint2*)(Pw + (quad * 4 + r) * 72 + l16 * 4) = wv;
    }
#pragma unroll
    for (int ks = 0; ks < 2; ks++) {
      const short8 ap = *(const short8*)(Pw + l16 * 72 + ks * 32 + quad * 8);
#pragma unroll
      for (int nj = 0; nj < 2; nj++) {
        const short8 bv = *(const short8*)(Vt + (nj * 16 + l16) * 264 + Q * 64 + ks * 32 + quad * 8);
        O[nj] = __builtin_amdgcn_mfma_f32_16x16x32_bf16(ap, bv, O[nj], 0, 0, 0);
      }
    }
  }
  // ---- epilogue: 1/l, gate sigmoid, stage in Pw, coalesced 16B stores ----
  const float* gbh = gb + h * 32;
#pragma unroll
  for (int nj = 0; nj < 2; nj++)
#pragma unroll
    for (int r = 0; r < 4; r++) {
      const int qg = q0 + quad * 4 + r;
      const int c = nj * 16 + l16;
      const float wa = O[nj][r] * li[r];
      const float gv = b2f(Yb[(size_t)qg * 1024 + 768 + h * 32 + c]) + gbh[c];
      const float gate = __builtin_amdgcn_rcpf(1.f + __expf(-gv));
      Pw[(quad * 4 + r) * 40 + c] = f2b(wa * gate);
    }
  {
    const int qr = lane >> 2, cc = (lane & 3) * 8;
    const uint4 zv = *(const uint4*)(Pw + qr * 40 + cc);
    *(uint4*)(Z + ((size_t)(b * 256 + q0 + qr)) * 256 + h * 32 + cc) = zv;
  }
}

extern "C" void kernel_launch(void* const* d_in, const int* in_sizes, int n_in,
                              void* d_out, int out_size, void* d_ws, size_t ws_size,
                              hipStream_t stream) {
  const float* msa  = (const float*)d_in[0];
  const float* mask = (const float*)d_in[1];
  const float* pair = (const float*)d_in[2];
  const float* qns  = (const float*)d_in[3];
  const float* qnb  = (const float*)d_in[4];
  const float* pns  = (const float*)d_in[5];
  const float* pnb  = (const float*)d_in[6];
  const float* f2w  = (const float*)d_in[7];
  const float* qw   = (const float*)d_in[8];
  const float* kw   = (const float*)d_in[9];
  const float* vw   = (const float*)d_in[10];
  const float* gw   = (const float*)d_in[11];
  const float* gbp  = (const float*)d_in[12];
  const float* ow   = (const float*)d_in[13];
  const float* ob   = (const float*)d_in[14];
  float* out = (float*)d_out;
  char* ws = (char*)d_ws;
  u16*   xb    = (u16*)(ws);                  // 16777216 B
  u16*   Wt    = (u16*)(ws + 16777216);       //   524288 B
  u16*   OWt   = (u16*)(ws + 17301504);       //   131072 B
  float* biasB = (float*)(ws + 17432576);     //  2097152 B
  u16*   Y     = (u16*)(ws + 19529728);       // 67108864 B
  u16*   Z     = (u16*)(ws + 86638592);       // 16777216 B

  k_prep<<<2128, 256, 0, stream>>>(msa, qns, qnb, pair, pns, pnb, f2w,
                                   qw, kw, vw, gw, ow, xb, biasB, Wt, OWt);
  k_gemm<true><<<dim3(256, 8), 256, 0, stream>>>(xb, Wt, (void*)Y, nullptr, 1024);
  k_attn<<<dim3(128, 8, 2), 512, 0, stream>>>(Y, biasB, mask, gbp, Z);
  k_gemm<false><<<dim3(256, 2), 256, 0, stream>>>(Z, OWt, (void*)out, ob, 256);
}